// Round 3
// baseline (1212.418 us; speedup 1.0000x reference)
//
#include <hip/hip_runtime.h>
#include <hip/hip_bf16.h>
#include <stdint.h>

#define NNODES 50000
#define NEDGES 800000
#define NF 128
#define NH 256
#define NTILES 12500
#define EGRID 256

typedef __attribute__((ext_vector_type(8))) __bf16 bf16x8;
typedef __attribute__((ext_vector_type(4))) float f32x4;

__device__ __forceinline__ unsigned short f2bf(float f) {
    union { float f; unsigned int u; } v; v.f = f;
    unsigned int r = v.u + 0x7fffu + ((v.u >> 16) & 1u);
    return (unsigned short)(r >> 16);
}

__device__ __forceinline__ void gload16(const void* g, void* l) {
    __builtin_amdgcn_global_load_lds(
        (const __attribute__((address_space(1))) void*)g,
        (__attribute__((address_space(3))) void*)l,
        16, 0, 0);
}

// f32 -> bf16 (vectorized), n4 = count of float4 groups
__global__ __launch_bounds__(256) void cvt_kernel(const float* __restrict__ src,
                                                  unsigned short* __restrict__ dst, int n4) {
    int i = blockIdx.x * 256 + threadIdx.x;
    if (i < n4) {
        const float4 v = ((const float4*)src)[i];
        ushort4 o;
        o.x = f2bf(v.x); o.y = f2bf(v.y); o.z = f2bf(v.z); o.w = f2bf(v.w);
        ((ushort4*)dst)[i] = o;
    }
}

// W [K][Nn] f32 row-major -> Wt [Nn][K] bf16
__global__ __launch_bounds__(256) void tcvt_kernel(const float* __restrict__ W,
                                                   unsigned short* __restrict__ Wt, int K, int Nn) {
    int i = blockIdx.x * 256 + threadIdx.x;
    if (i < K * Nn) {
        int k = i / Nn, n = i - k * Nn;
        Wt[n * K + k] = f2bf(W[i]);
    }
}

// ---------------- sort-by-row kernels ----------------
__global__ __launch_bounds__(256) void hist_kernel(const int* __restrict__ row, int* __restrict__ cnt) {
    int e = blockIdx.x * 256 + threadIdx.x;
    if (e < NEDGES) atomicAdd(&cnt[row[e]], 1);
}

__global__ __launch_bounds__(1024) void scan_kernel(const int* __restrict__ cnt, int* __restrict__ base, int n) {
    __shared__ int wsum[16];
    __shared__ int s_carry;
    const int tid = threadIdx.x;
    const int lane = tid & 63;
    const int wv = tid >> 6;
    if (tid == 0) s_carry = 0;
    __syncthreads();
    for (int off = 0; off < n; off += 1024) {
        int v = (off + tid < n) ? cnt[off + tid] : 0;
        int acc = v;
        #pragma unroll
        for (int s = 1; s < 64; s <<= 1) {
            int t = __shfl_up(acc, s);
            if (lane >= s) acc += t;
        }
        if (lane == 63) wsum[wv] = acc;
        __syncthreads();
        if (wv == 0) {
            int x = (lane < 16) ? wsum[lane] : 0;
            #pragma unroll
            for (int s = 1; s < 16; s <<= 1) {
                int t = __shfl_up(x, s);
                if (lane >= s) x += t;
            }
            if (lane < 16) wsum[lane] = x;
        }
        __syncthreads();
        int c = s_carry;
        int wtot = __shfl(acc, 63);
        int woff = wsum[wv] - wtot;
        if (off + tid < n) base[off + tid] = c + woff + acc - v;
        __syncthreads();
        if (tid == 0) s_carry = c + wsum[15];
        __syncthreads();
    }
}

__global__ __launch_bounds__(256) void scatter_kernel(const int* __restrict__ ei,
                                                      const int* __restrict__ base,
                                                      int* __restrict__ cursor,
                                                      int* __restrict__ ssrc,
                                                      int* __restrict__ sdst) {
    int e = blockIdx.x * 256 + threadIdx.x;
    if (e < NEDGES) {
        int r = ei[e];
        int c = ei[NEDGES + e];
        int pos = base[r] + atomicAdd(&cursor[r], 1);
        ssrc[pos] = r;
        sdst[pos] = c;
    }
}

// ---------------- edge kernel (persistent, register-resident weights) ----------------
// 512 threads = 8 waves; wave w owns output cols [w*32, w*32+32).
// Each block loops over a contiguous chunk of 64-edge tiles.
__global__ __launch_bounds__(512, 2)
void edge_kernel(const unsigned short* __restrict__ hbf,
                 const int* __restrict__ ssrc,
                 const int* __restrict__ sdst,
                 const unsigned short* __restrict__ Wt1,
                 const unsigned short* __restrict__ Wt2,
                 const float* __restrict__ b1, const float* __restrict__ g1,
                 const float* __restrict__ be1, const float* __restrict__ b2,
                 float* __restrict__ agg)
{
    __shared__ __align__(16) unsigned short A_lds[64 * 256];
    __shared__ __align__(16) unsigned short M_lds[64 * 256];
    __shared__ __align__(16) float S[64 * 260];
    __shared__ int s_srcb[2][64], s_dstb[2][64];
    __shared__ float s_mr[64][2];
    __shared__ float s_part[8][64][2];

    const int tid = threadIdx.x;
    const int lane = tid & 63;
    const int w = tid >> 6;
    const int l15 = lane & 15;
    const int g = lane >> 4;

    // ---- one-time: resident B fragments (both weights) + per-lane bias/LN params ----
    bf16x8 B1f[2][8], B2f[2][8];
    float b1r[2], g1r[2], be1r[2], b2r[2];
    #pragma unroll
    for (int n = 0; n < 2; ++n) {
        int cn = w * 32 + n * 16 + l15;
        b1r[n] = b1[cn]; g1r[n] = g1[cn]; be1r[n] = be1[cn]; b2r[n] = b2[cn];
        #pragma unroll
        for (int ks = 0; ks < 8; ++ks) {
            B1f[n][ks] = *(const bf16x8*)(const void*)&Wt1[cn * 256 + ks * 32 + 8 * g];
            B2f[n][ks] = *(const bf16x8*)(const void*)&Wt2[cn * 256 + ks * 32 + 8 * g];
        }
    }

    const int t0 = (int)(((long long)blockIdx.x * NTILES) / EGRID);
    const int t1 = (int)(((long long)(blockIdx.x + 1) * NTILES) / EGRID);

    // ---- A-tile stage: rows w*8..w*8+7, linear LDS dest, pre-swizzled global src ----
    auto STAGE = [&](int bufn, int tile) {
        int e0 = tile * 64;
        (void)e0;
        #pragma unroll
        for (int i = 0; i < 4; ++i) {
            int r0 = w * 8 + i * 2;
            int row = r0 + (lane >> 5);
            int gl = lane & 31;
            int ksrc = 8 * (gl ^ (row & 7));
            const int* ip = (ksrc < 128) ? &s_srcb[bufn][row] : &s_dstb[bufn][row];
            int nd = *ip;
            int ko = ksrc & 127;
            gload16(hbf + (size_t)nd * NF + ko, &A_lds[r0 * 256]);
        }
    };

    // ---- prologue: indices + stage for t0 ----
    if (tid < 64) s_srcb[0][tid] = ssrc[t0 * 64 + tid];
    else if (tid < 128) s_dstb[0][tid - 64] = sdst[t0 * 64 + (tid - 64)];
    __syncthreads();
    STAGE(0, t0);
    __syncthreads();

    for (int t = t0; t < t1; ++t) {
        const int buf = (t - t0) & 1;
        const bool more = (t + 1 < t1);

        // ---- GEMM1: e_in[64x256] @ W1 (B resident) ----
        f32x4 acc[4][2] = {};
        #pragma unroll
        for (int ks = 0; ks < 8; ++ks) {
            bf16x8 af[4];
            #pragma unroll
            for (int m = 0; m < 4; ++m) {
                int r = m * 16 + l15;
                af[m] = *(const bf16x8*)(const void*)&A_lds[r * 256 + ((ks * 32 + 8 * g) ^ ((r & 7) << 3))];
            }
            #pragma unroll
            for (int m = 0; m < 4; ++m)
                #pragma unroll
                for (int n = 0; n < 2; ++n)
                    acc[m][n] = __builtin_amdgcn_mfma_f32_16x16x32_bf16(af[m], B1f[n][ks], acc[m][n], 0, 0, 0);
        }

        // ---- bias + LN stats (32 cols/wave partials) ----
        float psum[4][4], psq[4][4];
        #pragma unroll
        for (int m = 0; m < 4; ++m)
            #pragma unroll
            for (int rr = 0; rr < 4; ++rr) { psum[m][rr] = 0.f; psq[m][rr] = 0.f; }
        #pragma unroll
        for (int m = 0; m < 4; ++m)
            #pragma unroll
            for (int n = 0; n < 2; ++n) {
                #pragma unroll
                for (int rr = 0; rr < 4; ++rr) {
                    float x = acc[m][n][rr] + b1r[n];
                    acc[m][n][rr] = x;
                    psum[m][rr] += x;
                    psq[m][rr] += x * x;
                }
            }
        #pragma unroll
        for (int m = 0; m < 4; ++m)
            #pragma unroll
            for (int rr = 0; rr < 4; ++rr) {
                float s = psum[m][rr], q = psq[m][rr];
                s += __shfl_xor(s, 1); s += __shfl_xor(s, 2); s += __shfl_xor(s, 4); s += __shfl_xor(s, 8);
                q += __shfl_xor(q, 1); q += __shfl_xor(q, 2); q += __shfl_xor(q, 4); q += __shfl_xor(q, 8);
                psum[m][rr] = s; psq[m][rr] = q;
            }
        float vs = 0.f, vq = 0.f;
        #pragma unroll
        for (int m = 0; m < 4; ++m)
            #pragma unroll
            for (int rr = 0; rr < 4; ++rr) {
                bool sel = (l15 == m * 4 + rr);
                vs = sel ? psum[m][rr] : vs;
                vq = sel ? psq[m][rr] : vq;
            }
        {
            int row = (l15 >> 2) * 16 + 4 * g + (l15 & 3);
            s_part[w][row][0] = vs;
            s_part[w][row][1] = vq;
        }
        __syncthreads();                               // B1
        if (tid < 64) {
            float s = 0.f, q = 0.f;
            #pragma unroll
            for (int ww = 0; ww < 8; ++ww) { s += s_part[ww][tid][0]; q += s_part[ww][tid][1]; }
            float mean = s * (1.f / 256.f);
            float var = q * (1.f / 256.f) - mean * mean;
            s_mr[tid][0] = mean;
            s_mr[tid][1] = rsqrtf(var + 1e-5f);
        }
        __syncthreads();                               // B2

        // ---- prefetch next tile's indices ----
        if (more) {
            if (tid < 64) s_srcb[buf ^ 1][tid] = ssrc[(t + 1) * 64 + tid];
            else if (tid < 128) s_dstb[buf ^ 1][tid - 64] = sdst[(t + 1) * 64 + (tid - 64)];
        }

        // ---- LN apply + SiLU -> M tile (bf16, swizzled) ----
        #pragma unroll
        for (int m = 0; m < 4; ++m)
            #pragma unroll
            for (int rr = 0; rr < 4; ++rr) {
                int row = m * 16 + 4 * g + rr;
                float mean = s_mr[row][0], rstd = s_mr[row][1];
                #pragma unroll
                for (int n = 0; n < 2; ++n) {
                    int col = w * 32 + n * 16 + l15;
                    float y = (acc[m][n][rr] - mean) * rstd * g1r[n] + be1r[n];
                    float sy = y * (1.f / (1.f + __expf(-y)));
                    M_lds[row * 256 + (col ^ ((row & 7) << 3))] = f2bf(sy);
                }
            }
        __syncthreads();                               // B3

        // ---- issue A-stage for t+1 (overlaps GEMM2) ----
        if (more) STAGE(buf ^ 1, t + 1);

        // ---- GEMM2: m[64x256] @ W2 (B resident) ----
        f32x4 acc2[4][2] = {};
        #pragma unroll
        for (int ks = 0; ks < 8; ++ks) {
            bf16x8 af[4];
            #pragma unroll
            for (int m = 0; m < 4; ++m) {
                int r = m * 16 + l15;
                af[m] = *(const bf16x8*)(const void*)&M_lds[r * 256 + ((ks * 32 + 8 * g) ^ ((r & 7) << 3))];
            }
            #pragma unroll
            for (int m = 0; m < 4; ++m)
                #pragma unroll
                for (int n = 0; n < 2; ++n)
                    acc2[m][n] = __builtin_amdgcn_mfma_f32_16x16x32_bf16(af[m], B2f[n][ks], acc2[m][n], 0, 0, 0);
        }

        // ---- S tile (f32) ----
        #pragma unroll
        for (int m = 0; m < 4; ++m)
            #pragma unroll
            for (int rr = 0; rr < 4; ++rr) {
                int row = m * 16 + 4 * g + rr;
                #pragma unroll
                for (int n = 0; n < 2; ++n) {
                    int col = w * 32 + n * 16 + l15;
                    S[row * 260 + col] = acc2[m][n][rr] + b2r[n];
                }
            }
        __syncthreads();                               // B4 (also drains stage vmcnt)

        // ---- run-reduce sorted rows, one atomic per run; 512 threads = 2 half-columns ----
        {
            int col = tid & 255;
            int rs = (tid >> 8) * 32;
            float run = 0.f;
            int prev = s_srcb[buf][rs];
            #pragma unroll 1
            for (int r = rs; r < rs + 32; ++r) {
                int nd = s_srcb[buf][r];
                if (nd != prev) {
                    atomicAdd(&agg[(size_t)prev * NH + col], run);
                    run = 0.f;
                    prev = nd;
                }
                run += S[r * 260 + col];
            }
            atomicAdd(&agg[(size_t)prev * NH + col], run);
        }
    }
}

// ---------------- node kernel ----------------
__global__ __launch_bounds__(256, 2)
void node_kernel(const float* __restrict__ h,
                 const unsigned short* __restrict__ hbf,
                 const unsigned short* __restrict__ aggbf,
                 const unsigned short* __restrict__ Wt3,
                 const unsigned short* __restrict__ Wt4,
                 const float* __restrict__ b3, const float* __restrict__ g2,
                 const float* __restrict__ be2, const float* __restrict__ b4,
                 float* __restrict__ out)
{
    __shared__ __align__(16) unsigned short A_lds[64 * 64];
    __shared__ __align__(16) unsigned short B_lds[256 * 64];
    __shared__ __align__(16) unsigned short M_lds[64 * 256];
    __shared__ float s_mr[64][2];
    __shared__ float s_b3[256], s_g2[256], s_be2[256], s_b4[128];

    const int tid = threadIdx.x;
    const int lane = tid & 63;
    const int w = tid >> 6;
    const int l15 = lane & 15;
    const int g = lane >> 4;
    const int r0 = blockIdx.x * 64;

    s_b3[tid] = b3[tid]; s_g2[tid] = g2[tid]; s_be2[tid] = be2[tid];
    if (tid < 128) s_b4[tid] = b4[tid];
    __syncthreads();

    f32x4 acc[4][4] = {};

    for (int kt = 0; kt < 6; ++kt) {
        #pragma unroll
        for (int i = 0; i < 2; ++i) {
            int c = i * 256 + w * 64 + lane;
            int r = c >> 3, kbl = c & 7;
            int kb = kbl ^ (r & 7);
            int nd = r0 + r; if (nd >= NNODES) nd = NNODES - 1;
            const unsigned short* src = (kt < 2)
                ? (hbf + (size_t)nd * NF + kt * 64 + kb * 8)
                : (aggbf + (size_t)nd * NH + (kt - 2) * 64 + kb * 8);
            gload16(src, &A_lds[(i * 256 + w * 64) * 8]);
        }
        #pragma unroll
        for (int i = 0; i < 8; ++i) {
            int c = i * 256 + w * 64 + lane;
            int n = c >> 3, kbl = c & 7;
            int kb = kbl ^ (n & 7);
            const unsigned short* src = Wt3 + n * 384 + kt * 64 + kb * 8;
            gload16(src, &B_lds[(i * 256 + w * 64) * 8]);
        }
        __syncthreads();
        #pragma unroll
        for (int kk = 0; kk < 2; ++kk) {
            int ke = kk * 32 + 8 * g;
            bf16x8 af[4], bfr[4];
            #pragma unroll
            for (int m = 0; m < 4; ++m) {
                int r = m * 16 + l15;
                af[m] = *(const bf16x8*)(const void*)&A_lds[r * 64 + (ke ^ ((r & 7) << 3))];
            }
            #pragma unroll
            for (int n = 0; n < 4; ++n) {
                int cn = w * 64 + n * 16 + l15;
                bfr[n] = *(const bf16x8*)(const void*)&B_lds[cn * 64 + (ke ^ ((cn & 7) << 3))];
            }
            #pragma unroll
            for (int m = 0; m < 4; ++m)
                #pragma unroll
                for (int n = 0; n < 4; ++n)
                    acc[m][n] = __builtin_amdgcn_mfma_f32_16x16x32_bf16(af[m], bfr[n], acc[m][n], 0, 0, 0);
        }
        __syncthreads();
    }

    float psum[4][4], psq[4][4];
    #pragma unroll
    for (int m = 0; m < 4; ++m)
        #pragma unroll
        for (int rr = 0; rr < 4; ++rr) { psum[m][rr] = 0.f; psq[m][rr] = 0.f; }
    #pragma unroll
    for (int m = 0; m < 4; ++m)
        #pragma unroll
        for (int n = 0; n < 4; ++n) {
            int col = w * 64 + n * 16 + l15;
            float bb = s_b3[col];
            #pragma unroll
            for (int rr = 0; rr < 4; ++rr) {
                float x = acc[m][n][rr] + bb;
                acc[m][n][rr] = x;
                psum[m][rr] += x;
                psq[m][rr] += x * x;
            }
        }
    #pragma unroll
    for (int m = 0; m < 4; ++m)
        #pragma unroll
        for (int rr = 0; rr < 4; ++rr) {
            float s = psum[m][rr], q = psq[m][rr];
            s += __shfl_xor(s, 1); s += __shfl_xor(s, 2); s += __shfl_xor(s, 4); s += __shfl_xor(s, 8);
            q += __shfl_xor(q, 1); q += __shfl_xor(q, 2); q += __shfl_xor(q, 4); q += __shfl_xor(q, 8);
            psum[m][rr] = s; psq[m][rr] = q;
        }
    float vs = 0.f, vq = 0.f;
    #pragma unroll
    for (int m = 0; m < 4; ++m)
        #pragma unroll
        for (int rr = 0; rr < 4; ++rr) {
            bool sel = (l15 == m * 4 + rr);
            vs = sel ? psum[m][rr] : vs;
            vq = sel ? psq[m][rr] : vq;
        }
    float (*s_part)[64][2] = (float(*)[64][2])(void*)M_lds;
    {
        int row = (l15 >> 2) * 16 + 4 * g + (l15 & 3);
        s_part[w][row][0] = vs;
        s_part[w][row][1] = vq;
    }
    __syncthreads();
    if (tid < 64) {
        float s = s_part[0][tid][0] + s_part[1][tid][0] + s_part[2][tid][0] + s_part[3][tid][0];
        float q = s_part[0][tid][1] + s_part[1][tid][1] + s_part[2][tid][1] + s_part[3][tid][1];
        float mean = s * (1.f / 256.f);
        float var = q * (1.f / 256.f) - mean * mean;
        s_mr[tid][0] = mean;
        s_mr[tid][1] = rsqrtf(var + 1e-5f);
    }
    __syncthreads();

    #pragma unroll
    for (int m = 0; m < 4; ++m)
        #pragma unroll
        for (int rr = 0; rr < 4; ++rr) {
            int row = m * 16 + 4 * g + rr;
            float mean = s_mr[row][0], rstd = s_mr[row][1];
            #pragma unroll
            for (int n = 0; n < 4; ++n) {
                int col = w * 64 + n * 16 + l15;
                float y = (acc[m][n][rr] - mean) * rstd * s_g2[col] + s_be2[col];
                float sy = y * (1.f / (1.f + __expf(-y)));
                M_lds[row * 256 + (col ^ ((row & 7) << 3))] = f2bf(sy);
            }
        }
    __syncthreads();

    f32x4 acc4[4][2] = {};
    for (int kt = 0; kt < 4; ++kt) {
        #pragma unroll
        for (int i = 0; i < 4; ++i) {
            int c = i * 256 + w * 64 + lane;
            int n = c >> 3, kbl = c & 7;
            int kb = kbl ^ (n & 7);
            const unsigned short* src = Wt4 + n * 256 + kt * 64 + kb * 8;
            gload16(src, &B_lds[(i * 256 + w * 64) * 8]);
        }
        __syncthreads();
        #pragma unroll
        for (int kk = 0; kk < 2; ++kk) {
            int keB = kk * 32 + 8 * g;
            int keA = kt * 64 + keB;
            bf16x8 af[4], bfr[2];
            #pragma unroll
            for (int m = 0; m < 4; ++m) {
                int r = m * 16 + l15;
                af[m] = *(const bf16x8*)(const void*)&M_lds[r * 256 + (keA ^ ((r & 7) << 3))];
            }
            #pragma unroll
            for (int n2 = 0; n2 < 2; ++n2) {
                int cn = w * 32 + n2 * 16 + l15;
                bfr[n2] = *(const bf16x8*)(const void*)&B_lds[cn * 64 + (keB ^ ((cn & 7) << 3))];
            }
            #pragma unroll
            for (int m = 0; m < 4; ++m)
                #pragma unroll
                for (int n2 = 0; n2 < 2; ++n2)
                    acc4[m][n2] = __builtin_amdgcn_mfma_f32_16x16x32_bf16(af[m], bfr[n2], acc4[m][n2], 0, 0, 0);
        }
        __syncthreads();
    }

    #pragma unroll
    for (int m = 0; m < 4; ++m)
        #pragma unroll
        for (int rr = 0; rr < 4; ++rr) {
            int row = m * 16 + 4 * g + rr;
            int nd = r0 + row;
            if (nd < NNODES) {
                #pragma unroll
                for (int n2 = 0; n2 < 2; ++n2) {
                    int col = w * 32 + n2 * 16 + l15;
                    out[(size_t)nd * NF + col] = h[(size_t)nd * NF + col] + acc4[m][n2][rr] + s_b4[col];
                }
            }
        }
}

extern "C" void kernel_launch(void* const* d_in, const int* in_sizes, int n_in,
                              void* d_out, int out_size, void* d_ws, size_t ws_size,
                              hipStream_t stream) {
    const float* h   = (const float*)d_in[0];
    const int* ei    = (const int*)d_in[1];
    const float* W1  = (const float*)d_in[2];
    const float* b1  = (const float*)d_in[3];
    const float* g1  = (const float*)d_in[4];
    const float* be1 = (const float*)d_in[5];
    const float* W2  = (const float*)d_in[6];
    const float* b2  = (const float*)d_in[7];
    const float* W3  = (const float*)d_in[8];
    const float* b3  = (const float*)d_in[9];
    const float* g2  = (const float*)d_in[10];
    const float* be2 = (const float*)d_in[11];
    const float* W4  = (const float*)d_in[12];
    const float* b4  = (const float*)d_in[13];
    float* out = (float*)d_out;

    char* ws = (char*)d_ws;
    float* agg            = (float*)(ws);                      // 51,200,000 B
    unsigned short* hbf   = (unsigned short*)(ws + 51200000);  // 12,800,000 B
    unsigned short* aggbf = (unsigned short*)(ws + 64000000);  // 25,600,000 B
    // ssrc/sdst overlay aggbf: live only [scatter, edge_kernel]; aggbf live [cvt2, node_kernel]
    int* ssrc             = (int*)(ws + 64000000);             // 3,200,000 B
    int* sdst             = (int*)(ws + 67200000);             // 3,200,000 B
    unsigned short* Wt1   = (unsigned short*)(ws + 89600000);  // 131,072 B
    unsigned short* Wt2   = (unsigned short*)(ws + 89731072);  // 131,072 B
    unsigned short* Wt3   = (unsigned short*)(ws + 89862144);  // 196,608 B
    unsigned short* Wt4   = (unsigned short*)(ws + 90058752);  // 65,536 B
    int* cnt              = (int*)(ws + 90124288);             // 200,000 B
    int* basep            = (int*)(ws + 90324288);             // 200,000 B
    int* cursor           = (int*)(ws + 90524288);             // 200,000 B

    hipMemsetAsync(agg, 0, (size_t)NNODES * NH * sizeof(float), stream);
    hipMemsetAsync(cnt, 0, NNODES * sizeof(int), stream);
    hipMemsetAsync(cursor, 0, NNODES * sizeof(int), stream);

    cvt_kernel<<<(NNODES * NF / 4 + 255) / 256, 256, 0, stream>>>(h, hbf, NNODES * NF / 4);
    tcvt_kernel<<<(256 * 256 + 255) / 256, 256, 0, stream>>>(W1, Wt1, 256, 256);
    tcvt_kernel<<<(256 * 256 + 255) / 256, 256, 0, stream>>>(W2, Wt2, 256, 256);
    tcvt_kernel<<<(384 * 256 + 255) / 256, 256, 0, stream>>>(W3, Wt3, 384, 256);
    tcvt_kernel<<<(256 * 128 + 255) / 256, 256, 0, stream>>>(W4, Wt4, 256, 128);

    hist_kernel<<<(NEDGES + 255) / 256, 256, 0, stream>>>(ei, cnt);
    scan_kernel<<<1, 1024, 0, stream>>>(cnt, basep, NNODES);
    scatter_kernel<<<(NEDGES + 255) / 256, 256, 0, stream>>>(ei, basep, cursor, ssrc, sdst);

    edge_kernel<<<EGRID, 512, 0, stream>>>(hbf, ssrc, sdst, Wt1, Wt2, b1, g1, be1, b2, agg);
    cvt_kernel<<<(NNODES * NH / 4 + 255) / 256, 256, 0, stream>>>(agg, aggbf, NNODES * NH / 4);
    node_kernel<<<(NNODES + 63) / 64, 256, 0, stream>>>(h, hbf, aggbf, Wt3, Wt4, b3, g2, be2, b4, out);
}

// Round 4
// 895.110 us; speedup vs baseline: 1.3545x; 1.3545x over previous
//
#include <hip/hip_runtime.h>
#include <hip/hip_bf16.h>
#include <stdint.h>

#define NNODES 50000
#define NEDGES 800000
#define NF 128
#define NH 256

typedef __attribute__((ext_vector_type(8))) __bf16 bf16x8;
typedef __attribute__((ext_vector_type(4))) float f32x4;

__device__ __forceinline__ unsigned short f2bf(float f) {
    union { float f; unsigned int u; } v; v.f = f;
    unsigned int r = v.u + 0x7fffu + ((v.u >> 16) & 1u);
    return (unsigned short)(r >> 16);
}

__device__ __forceinline__ void gload16(const void* g, void* l) {
    __builtin_amdgcn_global_load_lds(
        (const __attribute__((address_space(1))) void*)g,
        (__attribute__((address_space(3))) void*)l,
        16, 0, 0);
}

// f32 -> bf16 (vectorized), n4 = count of float4 groups
__global__ __launch_bounds__(256) void cvt_kernel(const float* __restrict__ src,
                                                  unsigned short* __restrict__ dst, int n4) {
    int i = blockIdx.x * 256 + threadIdx.x;
    if (i < n4) {
        const float4 v = ((const float4*)src)[i];
        ushort4 o;
        o.x = f2bf(v.x); o.y = f2bf(v.y); o.z = f2bf(v.z); o.w = f2bf(v.w);
        ((ushort4*)dst)[i] = o;
    }
}

// W [K][Nn] f32 row-major -> Wt [Nn][K] bf16
__global__ __launch_bounds__(256) void tcvt_kernel(const float* __restrict__ W,
                                                   unsigned short* __restrict__ Wt, int K, int Nn) {
    int i = blockIdx.x * 256 + threadIdx.x;
    if (i < K * Nn) {
        int k = i / Nn, n = i - k * Nn;
        Wt[n * K + k] = f2bf(W[i]);
    }
}

// ---------------- sort-by-row kernels ----------------
__global__ __launch_bounds__(256) void hist_kernel(const int* __restrict__ row, int* __restrict__ cnt) {
    int e = blockIdx.x * 256 + threadIdx.x;
    if (e < NEDGES) atomicAdd(&cnt[row[e]], 1);
}

__global__ __launch_bounds__(1024) void scan_kernel(const int* __restrict__ cnt, int* __restrict__ base, int n) {
    __shared__ int wsum[16];
    __shared__ int s_carry;
    const int tid = threadIdx.x;
    const int lane = tid & 63;
    const int wv = tid >> 6;
    if (tid == 0) s_carry = 0;
    __syncthreads();
    for (int off = 0; off < n; off += 1024) {
        int v = (off + tid < n) ? cnt[off + tid] : 0;
        int acc = v;
        #pragma unroll
        for (int s = 1; s < 64; s <<= 1) {
            int t = __shfl_up(acc, s);
            if (lane >= s) acc += t;
        }
        if (lane == 63) wsum[wv] = acc;
        __syncthreads();
        if (wv == 0) {
            int x = (lane < 16) ? wsum[lane] : 0;
            #pragma unroll
            for (int s = 1; s < 16; s <<= 1) {
                int t = __shfl_up(x, s);
                if (lane >= s) x += t;
            }
            if (lane < 16) wsum[lane] = x;
        }
        __syncthreads();
        int c = s_carry;
        int wtot = __shfl(acc, 63);
        int woff = wsum[wv] - wtot;
        if (off + tid < n) base[off + tid] = c + woff + acc - v;
        __syncthreads();
        if (tid == 0) s_carry = c + wsum[15];
        __syncthreads();
    }
}

__global__ __launch_bounds__(256) void scatter_kernel(const int* __restrict__ ei,
                                                      const int* __restrict__ base,
                                                      int* __restrict__ cursor,
                                                      int* __restrict__ ssrc,
                                                      int* __restrict__ sdst) {
    int e = blockIdx.x * 256 + threadIdx.x;
    if (e < NEDGES) {
        int r = ei[e];
        int c = ei[NEDGES + e];
        int pos = base[r] + atomicAdd(&cursor[r], 1);
        ssrc[pos] = r;
        sdst[pos] = c;
    }
}

// ---------------- edge kernel ----------------
// 64 sorted edges per block, 4 waves, wave w owns output cols [w*64, w*64+64).
// Weights read direct L2->VGPR (no B staging); epilogue = register run-reduce + atomics.
__global__ __launch_bounds__(256, 2)
void edge_kernel(const unsigned short* __restrict__ hbf,
                 const int* __restrict__ ssrc,
                 const int* __restrict__ sdst,
                 const unsigned short* __restrict__ Wt1,
                 const unsigned short* __restrict__ Wt2,
                 const float* __restrict__ b1, const float* __restrict__ g1,
                 const float* __restrict__ be1, const float* __restrict__ b2,
                 float* __restrict__ agg)
{
    __shared__ __align__(16) unsigned short A_lds[64 * 256];
    __shared__ __align__(16) unsigned short M_lds[64 * 256];
    __shared__ int s_src[64];
    __shared__ float s_mr[64][2];
    __shared__ float s_part[4][64][2];

    const int tid = threadIdx.x;
    const int lane = tid & 63;
    const int w = tid >> 6;
    const int l15 = lane & 15;
    const int g = lane >> 4;
    const int e0 = blockIdx.x * 64;

    // epilogue needs src ids in LDS
    if (tid < 64) s_src[tid] = ssrc[e0 + tid];

    // per-lane bias/LN params (cols this lane owns)
    float b1r[4], g1r[4], be1r[4], b2r[4];
    #pragma unroll
    for (int n = 0; n < 4; ++n) {
        int cn = w * 64 + n * 16 + l15;
        b1r[n] = b1[cn]; g1r[n] = g1[cn]; be1r[n] = be1[cn]; b2r[n] = b2[cn];
    }

    // ---- stage A tile (rows w*16..w*16+15), idx read direct from global ----
    // LDS chunk cc holds global k-chunk kc = cc ^ (row&7)  (chunk = 8 shorts)
    #pragma unroll
    for (int i = 0; i < 8; ++i) {
        int r0 = w * 16 + i * 2;
        int row = r0 + (lane >> 5);
        int cc = lane & 31;
        int kc = cc ^ (row & 7);
        int nd = (kc < 16) ? ssrc[e0 + row] : sdst[e0 + row];
        int ko = (kc & 15) * 8;
        gload16(hbf + (size_t)nd * NF + ko, &A_lds[r0 * 256]);
    }

    // ---- W1 fragments direct to registers (L2/L3-hot) ----
    bf16x8 Bf[4][8];
    #pragma unroll
    for (int n = 0; n < 4; ++n) {
        int cn = w * 64 + n * 16 + l15;
        #pragma unroll
        for (int ks = 0; ks < 8; ++ks)
            Bf[n][ks] = *(const bf16x8*)(const void*)&Wt1[cn * 256 + ks * 32 + 8 * g];
    }
    __syncthreads();                                   // drains A-stage + idx + Bf

    // ---- GEMM1: e_in[64x256] @ W1 ----
    f32x4 acc[4][4] = {};
    #pragma unroll
    for (int ks = 0; ks < 8; ++ks) {
        bf16x8 af[4];
        #pragma unroll
        for (int m = 0; m < 4; ++m) {
            int r = m * 16 + l15;
            af[m] = *(const bf16x8*)(const void*)&A_lds[r * 256 + ((ks * 32 + 8 * g) ^ ((r & 7) << 3))];
        }
        #pragma unroll
        for (int m = 0; m < 4; ++m)
            #pragma unroll
            for (int n = 0; n < 4; ++n)
                acc[m][n] = __builtin_amdgcn_mfma_f32_16x16x32_bf16(af[m], Bf[n][ks], acc[m][n], 0, 0, 0);
    }

    // ---- bias + LN stats ----
    float psum[4][4], psq[4][4];
    #pragma unroll
    for (int m = 0; m < 4; ++m)
        #pragma unroll
        for (int rr = 0; rr < 4; ++rr) { psum[m][rr] = 0.f; psq[m][rr] = 0.f; }
    #pragma unroll
    for (int m = 0; m < 4; ++m)
        #pragma unroll
        for (int n = 0; n < 4; ++n) {
            #pragma unroll
            for (int rr = 0; rr < 4; ++rr) {
                float x = acc[m][n][rr] + b1r[n];
                acc[m][n][rr] = x;
                psum[m][rr] += x;
                psq[m][rr] += x * x;
            }
        }
    #pragma unroll
    for (int m = 0; m < 4; ++m)
        #pragma unroll
        for (int rr = 0; rr < 4; ++rr) {
            float s = psum[m][rr], q = psq[m][rr];
            s += __shfl_xor(s, 1); s += __shfl_xor(s, 2); s += __shfl_xor(s, 4); s += __shfl_xor(s, 8);
            q += __shfl_xor(q, 1); q += __shfl_xor(q, 2); q += __shfl_xor(q, 4); q += __shfl_xor(q, 8);
            psum[m][rr] = s; psq[m][rr] = q;
        }
    float vs = 0.f, vq = 0.f;
    #pragma unroll
    for (int m = 0; m < 4; ++m)
        #pragma unroll
        for (int rr = 0; rr < 4; ++rr) {
            bool sel = (l15 == m * 4 + rr);
            vs = sel ? psum[m][rr] : vs;
            vq = sel ? psq[m][rr] : vq;
        }
    {
        int row = (l15 >> 2) * 16 + 4 * g + (l15 & 3);
        s_part[w][row][0] = vs;
        s_part[w][row][1] = vq;
    }
    __syncthreads();                                   // B1
    if (tid < 64) {
        float s = s_part[0][tid][0] + s_part[1][tid][0] + s_part[2][tid][0] + s_part[3][tid][0];
        float q = s_part[0][tid][1] + s_part[1][tid][1] + s_part[2][tid][1] + s_part[3][tid][1];
        float mean = s * (1.f / 256.f);
        float var = q * (1.f / 256.f) - mean * mean;
        s_mr[tid][0] = mean;
        s_mr[tid][1] = rsqrtf(var + 1e-5f);
    }
    __syncthreads();                                   // B2

    // ---- W2 fragments (issue now; latency hides under LN apply) ----
    #pragma unroll
    for (int n = 0; n < 4; ++n) {
        int cn = w * 64 + n * 16 + l15;
        #pragma unroll
        for (int ks = 0; ks < 8; ++ks)
            Bf[n][ks] = *(const bf16x8*)(const void*)&Wt2[cn * 256 + ks * 32 + 8 * g];
    }

    // ---- LN apply + SiLU -> M tile (bf16, swizzled) ----
    #pragma unroll
    for (int m = 0; m < 4; ++m)
        #pragma unroll
        for (int rr = 0; rr < 4; ++rr) {
            int row = m * 16 + 4 * g + rr;
            float mean = s_mr[row][0], rstd = s_mr[row][1];
            #pragma unroll
            for (int n = 0; n < 4; ++n) {
                int col = w * 64 + n * 16 + l15;
                float y = (acc[m][n][rr] - mean) * rstd * g1r[n] + be1r[n];
                float sy = y * (1.f / (1.f + __expf(-y)));
                M_lds[row * 256 + (col ^ ((row & 7) << 3))] = f2bf(sy);
            }
        }
    __syncthreads();                                   // B3 (M ready; Bf drained too)

    // ---- GEMM2: m[64x256] @ W2 ----
    f32x4 acc2[4][4] = {};
    #pragma unroll
    for (int ks = 0; ks < 8; ++ks) {
        bf16x8 af[4];
        #pragma unroll
        for (int m = 0; m < 4; ++m) {
            int r = m * 16 + l15;
            af[m] = *(const bf16x8*)(const void*)&M_lds[r * 256 + ((ks * 32 + 8 * g) ^ ((r & 7) << 3))];
        }
        #pragma unroll
        for (int m = 0; m < 4; ++m)
            #pragma unroll
            for (int n = 0; n < 4; ++n)
                acc2[m][n] = __builtin_amdgcn_mfma_f32_16x16x32_bf16(af[m], Bf[n][ks], acc2[m][n], 0, 0, 0);
    }

    // ---- epilogue: fold b2, register run-reduce over 4 consecutive sorted rows, atomics ----
    #pragma unroll
    for (int m = 0; m < 4; ++m) {
        int R0 = m * 16 + 4 * g;
        int nd0 = s_src[R0], nd1 = s_src[R0 + 1], nd2 = s_src[R0 + 2], nd3 = s_src[R0 + 3];
        bool k1 = (nd1 != nd0), k2 = (nd2 != nd1), k3 = (nd3 != nd2);
        #pragma unroll
        for (int n = 0; n < 4; ++n) {
            int col = w * 64 + n * 16 + l15;
            float* ap = agg + col;
            float run = acc2[m][n][0] + b2r[n];
            if (k1) { atomicAdd(ap + (size_t)nd0 * NH, run); run = 0.f; }
            run += acc2[m][n][1] + b2r[n];
            if (k2) { atomicAdd(ap + (size_t)nd1 * NH, run); run = 0.f; }
            run += acc2[m][n][2] + b2r[n];
            if (k3) { atomicAdd(ap + (size_t)nd2 * NH, run); run = 0.f; }
            run += acc2[m][n][3] + b2r[n];
            atomicAdd(ap + (size_t)nd3 * NH, run);
        }
    }
}

// ---------------- node kernel ----------------
__global__ __launch_bounds__(256, 2)
void node_kernel(const float* __restrict__ h,
                 const unsigned short* __restrict__ hbf,
                 const unsigned short* __restrict__ aggbf,
                 const unsigned short* __restrict__ Wt3,
                 const unsigned short* __restrict__ Wt4,
                 const float* __restrict__ b3, const float* __restrict__ g2,
                 const float* __restrict__ be2, const float* __restrict__ b4,
                 float* __restrict__ out)
{
    __shared__ __align__(16) unsigned short A_lds[64 * 64];
    __shared__ __align__(16) unsigned short B_lds[256 * 64];
    __shared__ __align__(16) unsigned short M_lds[64 * 256];
    __shared__ float s_mr[64][2];
    __shared__ float s_b3[256], s_g2[256], s_be2[256], s_b4[128];

    const int tid = threadIdx.x;
    const int lane = tid & 63;
    const int w = tid >> 6;
    const int l15 = lane & 15;
    const int g = lane >> 4;
    const int r0 = blockIdx.x * 64;

    s_b3[tid] = b3[tid]; s_g2[tid] = g2[tid]; s_be2[tid] = be2[tid];
    if (tid < 128) s_b4[tid] = b4[tid];
    __syncthreads();

    f32x4 acc[4][4] = {};

    for (int kt = 0; kt < 6; ++kt) {
        #pragma unroll
        for (int i = 0; i < 2; ++i) {
            int c = i * 256 + w * 64 + lane;
            int r = c >> 3, kbl = c & 7;
            int kb = kbl ^ (r & 7);
            int nd = r0 + r; if (nd >= NNODES) nd = NNODES - 1;
            const unsigned short* src = (kt < 2)
                ? (hbf + (size_t)nd * NF + kt * 64 + kb * 8)
                : (aggbf + (size_t)nd * NH + (kt - 2) * 64 + kb * 8);
            gload16(src, &A_lds[(i * 256 + w * 64) * 8]);
        }
        #pragma unroll
        for (int i = 0; i < 8; ++i) {
            int c = i * 256 + w * 64 + lane;
            int n = c >> 3, kbl = c & 7;
            int kb = kbl ^ (n & 7);
            const unsigned short* src = Wt3 + n * 384 + kt * 64 + kb * 8;
            gload16(src, &B_lds[(i * 256 + w * 64) * 8]);
        }
        __syncthreads();
        #pragma unroll
        for (int kk = 0; kk < 2; ++kk) {
            int ke = kk * 32 + 8 * g;
            bf16x8 af[4], bfr[4];
            #pragma unroll
            for (int m = 0; m < 4; ++m) {
                int r = m * 16 + l15;
                af[m] = *(const bf16x8*)(const void*)&A_lds[r * 64 + (ke ^ ((r & 7) << 3))];
            }
            #pragma unroll
            for (int n = 0; n < 4; ++n) {
                int cn = w * 64 + n * 16 + l15;
                bfr[n] = *(const bf16x8*)(const void*)&B_lds[cn * 64 + (ke ^ ((cn & 7) << 3))];
            }
            #pragma unroll
            for (int m = 0; m < 4; ++m)
                #pragma unroll
                for (int n = 0; n < 4; ++n)
                    acc[m][n] = __builtin_amdgcn_mfma_f32_16x16x32_bf16(af[m], bfr[n], acc[m][n], 0, 0, 0);
        }
        __syncthreads();
    }

    float psum[4][4], psq[4][4];
    #pragma unroll
    for (int m = 0; m < 4; ++m)
        #pragma unroll
        for (int rr = 0; rr < 4; ++rr) { psum[m][rr] = 0.f; psq[m][rr] = 0.f; }
    #pragma unroll
    for (int m = 0; m < 4; ++m)
        #pragma unroll
        for (int n = 0; n < 4; ++n) {
            int col = w * 64 + n * 16 + l15;
            float bb = s_b3[col];
            #pragma unroll
            for (int rr = 0; rr < 4; ++rr) {
                float x = acc[m][n][rr] + bb;
                acc[m][n][rr] = x;
                psum[m][rr] += x;
                psq[m][rr] += x * x;
            }
        }
    #pragma unroll
    for (int m = 0; m < 4; ++m)
        #pragma unroll
        for (int rr = 0; rr < 4; ++rr) {
            float s = psum[m][rr], q = psq[m][rr];
            s += __shfl_xor(s, 1); s += __shfl_xor(s, 2); s += __shfl_xor(s, 4); s += __shfl_xor(s, 8);
            q += __shfl_xor(q, 1); q += __shfl_xor(q, 2); q += __shfl_xor(q, 4); q += __shfl_xor(q, 8);
            psum[m][rr] = s; psq[m][rr] = q;
        }
    float vs = 0.f, vq = 0.f;
    #pragma unroll
    for (int m = 0; m < 4; ++m)
        #pragma unroll
        for (int rr = 0; rr < 4; ++rr) {
            bool sel = (l15 == m * 4 + rr);
            vs = sel ? psum[m][rr] : vs;
            vq = sel ? psq[m][rr] : vq;
        }
    float (*s_part)[64][2] = (float(*)[64][2])(void*)M_lds;
    {
        int row = (l15 >> 2) * 16 + 4 * g + (l15 & 3);
        s_part[w][row][0] = vs;
        s_part[w][row][1] = vq;
    }
    __syncthreads();
    if (tid < 64) {
        float s = s_part[0][tid][0] + s_part[1][tid][0] + s_part[2][tid][0] + s_part[3][tid][0];
        float q = s_part[0][tid][1] + s_part[1][tid][1] + s_part[2][tid][1] + s_part[3][tid][1];
        float mean = s * (1.f / 256.f);
        float var = q * (1.f / 256.f) - mean * mean;
        s_mr[tid][0] = mean;
        s_mr[tid][1] = rsqrtf(var + 1e-5f);
    }
    __syncthreads();

    #pragma unroll
    for (int m = 0; m < 4; ++m)
        #pragma unroll
        for (int rr = 0; rr < 4; ++rr) {
            int row = m * 16 + 4 * g + rr;
            float mean = s_mr[row][0], rstd = s_mr[row][1];
            #pragma unroll
            for (int n = 0; n < 4; ++n) {
                int col = w * 64 + n * 16 + l15;
                float y = (acc[m][n][rr] - mean) * rstd * s_g2[col] + s_be2[col];
                float sy = y * (1.f / (1.f + __expf(-y)));
                M_lds[row * 256 + (col ^ ((row & 7) << 3))] = f2bf(sy);
            }
        }
    __syncthreads();

    f32x4 acc4[4][2] = {};
    for (int kt = 0; kt < 4; ++kt) {
        #pragma unroll
        for (int i = 0; i < 4; ++i) {
            int c = i * 256 + w * 64 + lane;
            int n = c >> 3, kbl = c & 7;
            int kb = kbl ^ (n & 7);
            const unsigned short* src = Wt4 + n * 256 + kt * 64 + kb * 8;
            gload16(src, &B_lds[(i * 256 + w * 64) * 8]);
        }
        __syncthreads();
        #pragma unroll
        for (int kk = 0; kk < 2; ++kk) {
            int keB = kk * 32 + 8 * g;
            int keA = kt * 64 + keB;
            bf16x8 af[4], bfr[2];
            #pragma unroll
            for (int m = 0; m < 4; ++m) {
                int r = m * 16 + l15;
                af[m] = *(const bf16x8*)(const void*)&M_lds[r * 256 + (keA ^ ((r & 7) << 3))];
            }
            #pragma unroll
            for (int n2 = 0; n2 < 2; ++n2) {
                int cn = w * 32 + n2 * 16 + l15;
                bfr[n2] = *(const bf16x8*)(const void*)&B_lds[cn * 64 + (keB ^ ((cn & 7) << 3))];
            }
            #pragma unroll
            for (int m = 0; m < 4; ++m)
                #pragma unroll
                for (int n2 = 0; n2 < 2; ++n2)
                    acc4[m][n2] = __builtin_amdgcn_mfma_f32_16x16x32_bf16(af[m], bfr[n2], acc4[m][n2], 0, 0, 0);
        }
        __syncthreads();
    }

    #pragma unroll
    for (int m = 0; m < 4; ++m)
        #pragma unroll
        for (int rr = 0; rr < 4; ++rr) {
            int row = m * 16 + 4 * g + rr;
            int nd = r0 + row;
            if (nd < NNODES) {
                #pragma unroll
                for (int n2 = 0; n2 < 2; ++n2) {
                    int col = w * 32 + n2 * 16 + l15;
                    out[(size_t)nd * NF + col] = h[(size_t)nd * NF + col] + acc4[m][n2][rr] + s_b4[col];
                }
            }
        }
}

extern "C" void kernel_launch(void* const* d_in, const int* in_sizes, int n_in,
                              void* d_out, int out_size, void* d_ws, size_t ws_size,
                              hipStream_t stream) {
    const float* h   = (const float*)d_in[0];
    const int* ei    = (const int*)d_in[1];
    const float* W1  = (const float*)d_in[2];
    const float* b1  = (const float*)d_in[3];
    const float* g1  = (const float*)d_in[4];
    const float* be1 = (const float*)d_in[5];
    const float* W2  = (const float*)d_in[6];
    const float* b2  = (const float*)d_in[7];
    const float* W3  = (const float*)d_in[8];
    const float* b3  = (const float*)d_in[9];
    const float* g2  = (const float*)d_in[10];
    const float* be2 = (const float*)d_in[11];
    const float* W4  = (const float*)d_in[12];
    const float* b4  = (const float*)d_in[13];
    float* out = (float*)d_out;

    char* ws = (char*)d_ws;
    float* agg            = (float*)(ws);                      // 51,200,000 B
    unsigned short* hbf   = (unsigned short*)(ws + 51200000);  // 12,800,000 B
    unsigned short* aggbf = (unsigned short*)(ws + 64000000);  // 25,600,000 B
    // ssrc/sdst overlay aggbf: live only [scatter, edge_kernel]; aggbf live [cvt2, node_kernel]
    int* ssrc             = (int*)(ws + 64000000);             // 3,200,000 B
    int* sdst             = (int*)(ws + 67200000);             // 3,200,000 B
    unsigned short* Wt1   = (unsigned short*)(ws + 89600000);  // 131,072 B
    unsigned short* Wt2   = (unsigned short*)(ws + 89731072);  // 131,072 B
    unsigned short* Wt3   = (unsigned short*)(ws + 89862144);  // 196,608 B
    unsigned short* Wt4   = (unsigned short*)(ws + 90058752);  // 65,536 B
    int* cnt              = (int*)(ws + 90124288);             // 200,000 B
    int* basep            = (int*)(ws + 90324288);             // 200,000 B
    int* cursor           = (int*)(ws + 90524288);             // 200,000 B

    hipMemsetAsync(agg, 0, (size_t)NNODES * NH * sizeof(float), stream);
    hipMemsetAsync(cnt, 0, NNODES * sizeof(int), stream);
    hipMemsetAsync(cursor, 0, NNODES * sizeof(int), stream);

    cvt_kernel<<<(NNODES * NF / 4 + 255) / 256, 256, 0, stream>>>(h, hbf, NNODES * NF / 4);
    tcvt_kernel<<<(256 * 256 + 255) / 256, 256, 0, stream>>>(W1, Wt1, 256, 256);
    tcvt_kernel<<<(256 * 256 + 255) / 256, 256, 0, stream>>>(W2, Wt2, 256, 256);
    tcvt_kernel<<<(384 * 256 + 255) / 256, 256, 0, stream>>>(W3, Wt3, 384, 256);
    tcvt_kernel<<<(256 * 128 + 255) / 256, 256, 0, stream>>>(W4, Wt4, 256, 128);

    hist_kernel<<<(NEDGES + 255) / 256, 256, 0, stream>>>(ei, cnt);
    scan_kernel<<<1, 1024, 0, stream>>>(cnt, basep, NNODES);
    scatter_kernel<<<(NEDGES + 255) / 256, 256, 0, stream>>>(ei, basep, cursor, ssrc, sdst);

    edge_kernel<<<NEDGES / 64, 256, 0, stream>>>(hbf, ssrc, sdst, Wt1, Wt2, b1, g1, be1, b2, agg);
    cvt_kernel<<<(NNODES * NH / 4 + 255) / 256, 256, 0, stream>>>(agg, aggbf, NNODES * NH / 4);
    node_kernel<<<(NNODES + 63) / 64, 256, 0, stream>>>(h, hbf, aggbf, Wt3, Wt4, b3, g2, be2, b4, out);
}

// Round 5
// 783.814 us; speedup vs baseline: 1.5468x; 1.1420x over previous
//
#include <hip/hip_runtime.h>
#include <hip/hip_bf16.h>
#include <stdint.h>

#define NNODES 50000
#define NEDGES 800000
#define NF 128
#define NH 256

typedef __attribute__((ext_vector_type(8))) __bf16 bf16x8;
typedef __attribute__((ext_vector_type(4))) float f32x4;

__device__ __forceinline__ unsigned short f2bf(float f) {
    union { float f; unsigned int u; } v; v.f = f;
    unsigned int r = v.u + 0x7fffu + ((v.u >> 16) & 1u);
    return (unsigned short)(r >> 16);
}

__device__ __forceinline__ void gload16(const void* g, void* l) {
    __builtin_amdgcn_global_load_lds(
        (const __attribute__((address_space(1))) void*)g,
        (__attribute__((address_space(3))) void*)l,
        16, 0, 0);
}

// f32 -> bf16 (vectorized), n4 = count of float4 groups
__global__ __launch_bounds__(256) void cvt_kernel(const float* __restrict__ src,
                                                  unsigned short* __restrict__ dst, int n4) {
    int i = blockIdx.x * 256 + threadIdx.x;
    if (i < n4) {
        const float4 v = ((const float4*)src)[i];
        ushort4 o;
        o.x = f2bf(v.x); o.y = f2bf(v.y); o.z = f2bf(v.z); o.w = f2bf(v.w);
        ((ushort4*)dst)[i] = o;
    }
}

// W [K][Nn] f32 row-major -> Wt [Nn][K] bf16
__global__ __launch_bounds__(256) void tcvt_kernel(const float* __restrict__ W,
                                                   unsigned short* __restrict__ Wt, int K, int Nn) {
    int i = blockIdx.x * 256 + threadIdx.x;
    if (i < K * Nn) {
        int k = i / Nn, n = i - k * Nn;
        Wt[n * K + k] = f2bf(W[i]);
    }
}

// ---------------- sort-by-row kernels ----------------
__global__ __launch_bounds__(256) void hist_kernel(const int* __restrict__ row, int* __restrict__ cnt) {
    int e = blockIdx.x * 256 + threadIdx.x;
    if (e < NEDGES) atomicAdd(&cnt[row[e]], 1);
}

__global__ __launch_bounds__(1024) void scan_kernel(const int* __restrict__ cnt, int* __restrict__ base, int n) {
    __shared__ int wsum[16];
    __shared__ int s_carry;
    const int tid = threadIdx.x;
    const int lane = tid & 63;
    const int wv = tid >> 6;
    if (tid == 0) s_carry = 0;
    __syncthreads();
    for (int off = 0; off < n; off += 1024) {
        int v = (off + tid < n) ? cnt[off + tid] : 0;
        int acc = v;
        #pragma unroll
        for (int s = 1; s < 64; s <<= 1) {
            int t = __shfl_up(acc, s);
            if (lane >= s) acc += t;
        }
        if (lane == 63) wsum[wv] = acc;
        __syncthreads();
        if (wv == 0) {
            int x = (lane < 16) ? wsum[lane] : 0;
            #pragma unroll
            for (int s = 1; s < 16; s <<= 1) {
                int t = __shfl_up(x, s);
                if (lane >= s) x += t;
            }
            if (lane < 16) wsum[lane] = x;
        }
        __syncthreads();
        int c = s_carry;
        int wtot = __shfl(acc, 63);
        int woff = wsum[wv] - wtot;
        if (off + tid < n) base[off + tid] = c + woff + acc - v;
        __syncthreads();
        if (tid == 0) s_carry = c + wsum[15];
        __syncthreads();
    }
}

__global__ __launch_bounds__(256) void scatter_kernel(const int* __restrict__ ei,
                                                      const int* __restrict__ base,
                                                      int* __restrict__ cursor,
                                                      int* __restrict__ ssrc,
                                                      int* __restrict__ sdst) {
    int e = blockIdx.x * 256 + threadIdx.x;
    if (e < NEDGES) {
        int r = ei[e];
        int c = ei[NEDGES + e];
        int pos = base[r] + atomicAdd(&cursor[r], 1);
        ssrc[pos] = r;
        sdst[pos] = c;
    }
}

// ---------------- edge kernel ----------------
// 64 sorted edges per block, 4 waves, wave w owns output cols [w*64, w*64+64).
// Weights direct L2->VGPR (no B staging). Epilogue: S-tile in LDS + per-column
// run-reduce over sorted rows (one atomic per run) — the r2 low-traffic scheme.
__global__ __launch_bounds__(256, 2)
void edge_kernel(const unsigned short* __restrict__ hbf,
                 const int* __restrict__ ssrc,
                 const int* __restrict__ sdst,
                 const unsigned short* __restrict__ Wt1,
                 const unsigned short* __restrict__ Wt2,
                 const float* __restrict__ b1, const float* __restrict__ g1,
                 const float* __restrict__ be1, const float* __restrict__ b2,
                 float* __restrict__ agg)
{
    // A (32768 B) | M (32768 B); S f32 64x260 (66560 B) overlays both after GEMM2
    __shared__ __align__(16) char smem[66560];
    unsigned short* A_lds = (unsigned short*)smem;
    unsigned short* M_lds = (unsigned short*)(smem + 32768);
    float* S = (float*)smem;
    __shared__ int s_src[64];
    __shared__ float s_mr[64][2];
    __shared__ float s_part[4][64][2];

    const int tid = threadIdx.x;
    const int lane = tid & 63;
    const int w = tid >> 6;
    const int l15 = lane & 15;
    const int g = lane >> 4;
    const int e0 = blockIdx.x * 64;

    // epilogue needs src ids in LDS
    if (tid < 64) s_src[tid] = ssrc[e0 + tid];

    // per-lane bias/LN params (cols this lane owns)
    float b1r[4], g1r[4], be1r[4], b2r[4];
    #pragma unroll
    for (int n = 0; n < 4; ++n) {
        int cn = w * 64 + n * 16 + l15;
        b1r[n] = b1[cn]; g1r[n] = g1[cn]; be1r[n] = be1[cn]; b2r[n] = b2[cn];
    }

    // ---- stage A tile (rows w*16..w*16+15), idx read direct from global ----
    // LDS chunk cc holds global k-chunk kc = cc ^ (row&7)  (chunk = 8 shorts)
    #pragma unroll
    for (int i = 0; i < 8; ++i) {
        int r0 = w * 16 + i * 2;
        int row = r0 + (lane >> 5);
        int cc = lane & 31;
        int kc = cc ^ (row & 7);
        int nd = (kc < 16) ? ssrc[e0 + row] : sdst[e0 + row];
        int ko = (kc & 15) * 8;
        gload16(hbf + (size_t)nd * NF + ko, &A_lds[r0 * 256]);
    }

    // ---- W1 fragments direct to registers (L2/L3-hot) ----
    bf16x8 Bf[4][8];
    #pragma unroll
    for (int n = 0; n < 4; ++n) {
        int cn = w * 64 + n * 16 + l15;
        #pragma unroll
        for (int ks = 0; ks < 8; ++ks)
            Bf[n][ks] = *(const bf16x8*)(const void*)&Wt1[cn * 256 + ks * 32 + 8 * g];
    }
    __syncthreads();                                   // B0: A-stage + idx drained

    // ---- GEMM1: e_in[64x256] @ W1 ----
    f32x4 acc[4][4] = {};
    #pragma unroll
    for (int ks = 0; ks < 8; ++ks) {
        bf16x8 af[4];
        #pragma unroll
        for (int m = 0; m < 4; ++m) {
            int r = m * 16 + l15;
            af[m] = *(const bf16x8*)(const void*)&A_lds[r * 256 + ((ks * 32 + 8 * g) ^ ((r & 7) << 3))];
        }
        #pragma unroll
        for (int m = 0; m < 4; ++m)
            #pragma unroll
            for (int n = 0; n < 4; ++n)
                acc[m][n] = __builtin_amdgcn_mfma_f32_16x16x32_bf16(af[m], Bf[n][ks], acc[m][n], 0, 0, 0);
    }

    // ---- bias + LN stats ----
    float psum[4][4], psq[4][4];
    #pragma unroll
    for (int m = 0; m < 4; ++m)
        #pragma unroll
        for (int rr = 0; rr < 4; ++rr) { psum[m][rr] = 0.f; psq[m][rr] = 0.f; }
    #pragma unroll
    for (int m = 0; m < 4; ++m)
        #pragma unroll
        for (int n = 0; n < 4; ++n) {
            #pragma unroll
            for (int rr = 0; rr < 4; ++rr) {
                float x = acc[m][n][rr] + b1r[n];
                acc[m][n][rr] = x;
                psum[m][rr] += x;
                psq[m][rr] += x * x;
            }
        }
    #pragma unroll
    for (int m = 0; m < 4; ++m)
        #pragma unroll
        for (int rr = 0; rr < 4; ++rr) {
            float s = psum[m][rr], q = psq[m][rr];
            s += __shfl_xor(s, 1); s += __shfl_xor(s, 2); s += __shfl_xor(s, 4); s += __shfl_xor(s, 8);
            q += __shfl_xor(q, 1); q += __shfl_xor(q, 2); q += __shfl_xor(q, 4); q += __shfl_xor(q, 8);
            psum[m][rr] = s; psq[m][rr] = q;
        }
    float vs = 0.f, vq = 0.f;
    #pragma unroll
    for (int m = 0; m < 4; ++m)
        #pragma unroll
        for (int rr = 0; rr < 4; ++rr) {
            bool sel = (l15 == m * 4 + rr);
            vs = sel ? psum[m][rr] : vs;
            vq = sel ? psq[m][rr] : vq;
        }
    {
        int row = (l15 >> 2) * 16 + 4 * g + (l15 & 3);
        s_part[w][row][0] = vs;
        s_part[w][row][1] = vq;
    }
    __syncthreads();                                   // B1
    if (tid < 64) {
        float s = s_part[0][tid][0] + s_part[1][tid][0] + s_part[2][tid][0] + s_part[3][tid][0];
        float q = s_part[0][tid][1] + s_part[1][tid][1] + s_part[2][tid][1] + s_part[3][tid][1];
        float mean = s * (1.f / 256.f);
        float var = q * (1.f / 256.f) - mean * mean;
        s_mr[tid][0] = mean;
        s_mr[tid][1] = rsqrtf(var + 1e-5f);
    }
    __syncthreads();                                   // B2

    // ---- W2 fragments (issue now; latency hides under LN apply) ----
    #pragma unroll
    for (int n = 0; n < 4; ++n) {
        int cn = w * 64 + n * 16 + l15;
        #pragma unroll
        for (int ks = 0; ks < 8; ++ks)
            Bf[n][ks] = *(const bf16x8*)(const void*)&Wt2[cn * 256 + ks * 32 + 8 * g];
    }

    // ---- LN apply + SiLU -> M tile (bf16, swizzled) ----
    #pragma unroll
    for (int m = 0; m < 4; ++m)
        #pragma unroll
        for (int rr = 0; rr < 4; ++rr) {
            int row = m * 16 + 4 * g + rr;
            float mean = s_mr[row][0], rstd = s_mr[row][1];
            #pragma unroll
            for (int n = 0; n < 4; ++n) {
                int col = w * 64 + n * 16 + l15;
                float y = (acc[m][n][rr] - mean) * rstd * g1r[n] + be1r[n];
                float sy = y * (1.f / (1.f + __expf(-y)));
                M_lds[row * 256 + (col ^ ((row & 7) << 3))] = f2bf(sy);
            }
        }
    __syncthreads();                                   // B3: M ready, Bf drained

    // ---- GEMM2: m[64x256] @ W2 ----
    f32x4 acc2[4][4] = {};
    #pragma unroll
    for (int ks = 0; ks < 8; ++ks) {
        bf16x8 af[4];
        #pragma unroll
        for (int m = 0; m < 4; ++m) {
            int r = m * 16 + l15;
            af[m] = *(const bf16x8*)(const void*)&M_lds[r * 256 + ((ks * 32 + 8 * g) ^ ((r & 7) << 3))];
        }
        #pragma unroll
        for (int m = 0; m < 4; ++m)
            #pragma unroll
            for (int n = 0; n < 4; ++n)
                acc2[m][n] = __builtin_amdgcn_mfma_f32_16x16x32_bf16(af[m], Bf[n][ks], acc2[m][n], 0, 0, 0);
    }
    __syncthreads();                                   // B4: all M reads done, S may overlay

    // ---- S tile (f32, stride 260) ----
    #pragma unroll
    for (int m = 0; m < 4; ++m)
        #pragma unroll
        for (int rr = 0; rr < 4; ++rr) {
            int row = m * 16 + 4 * g + rr;
            #pragma unroll
            for (int n = 0; n < 4; ++n) {
                int col = w * 64 + n * 16 + l15;
                S[row * 260 + col] = acc2[m][n][rr] + b2r[n];
            }
        }
    __syncthreads();                                   // B5: S ready

    // ---- per-column run-reduce over sorted rows, one atomic per run ----
    {
        int col = tid;
        float run = 0.f;
        int prev = s_src[0];
        #pragma unroll 1
        for (int r = 0; r < 64; ++r) {
            int nd = s_src[r];
            if (nd != prev) {
                atomicAdd(&agg[(size_t)prev * NH + col], run);
                run = 0.f;
                prev = nd;
            }
            run += S[r * 260 + col];
        }
        atomicAdd(&agg[(size_t)prev * NH + col], run);
    }
}

// ---------------- node kernel ----------------
__global__ __launch_bounds__(256, 2)
void node_kernel(const float* __restrict__ h,
                 const unsigned short* __restrict__ hbf,
                 const unsigned short* __restrict__ aggbf,
                 const unsigned short* __restrict__ Wt3,
                 const unsigned short* __restrict__ Wt4,
                 const float* __restrict__ b3, const float* __restrict__ g2,
                 const float* __restrict__ be2, const float* __restrict__ b4,
                 float* __restrict__ out)
{
    __shared__ __align__(16) unsigned short A_lds[64 * 64];
    __shared__ __align__(16) unsigned short B_lds[256 * 64];
    __shared__ __align__(16) unsigned short M_lds[64 * 256];
    __shared__ float s_mr[64][2];
    __shared__ float s_b3[256], s_g2[256], s_be2[256], s_b4[128];

    const int tid = threadIdx.x;
    const int lane = tid & 63;
    const int w = tid >> 6;
    const int l15 = lane & 15;
    const int g = lane >> 4;
    const int r0 = blockIdx.x * 64;

    s_b3[tid] = b3[tid]; s_g2[tid] = g2[tid]; s_be2[tid] = be2[tid];
    if (tid < 128) s_b4[tid] = b4[tid];
    __syncthreads();

    f32x4 acc[4][4] = {};

    for (int kt = 0; kt < 6; ++kt) {
        #pragma unroll
        for (int i = 0; i < 2; ++i) {
            int c = i * 256 + w * 64 + lane;
            int r = c >> 3, kbl = c & 7;
            int kb = kbl ^ (r & 7);
            int nd = r0 + r; if (nd >= NNODES) nd = NNODES - 1;
            const unsigned short* src = (kt < 2)
                ? (hbf + (size_t)nd * NF + kt * 64 + kb * 8)
                : (aggbf + (size_t)nd * NH + (kt - 2) * 64 + kb * 8);
            gload16(src, &A_lds[(i * 256 + w * 64) * 8]);
        }
        #pragma unroll
        for (int i = 0; i < 8; ++i) {
            int c = i * 256 + w * 64 + lane;
            int n = c >> 3, kbl = c & 7;
            int kb = kbl ^ (n & 7);
            const unsigned short* src = Wt3 + n * 384 + kt * 64 + kb * 8;
            gload16(src, &B_lds[(i * 256 + w * 64) * 8]);
        }
        __syncthreads();
        #pragma unroll
        for (int kk = 0; kk < 2; ++kk) {
            int ke = kk * 32 + 8 * g;
            bf16x8 af[4], bfr[4];
            #pragma unroll
            for (int m = 0; m < 4; ++m) {
                int r = m * 16 + l15;
                af[m] = *(const bf16x8*)(const void*)&A_lds[r * 64 + (ke ^ ((r & 7) << 3))];
            }
            #pragma unroll
            for (int n = 0; n < 4; ++n) {
                int cn = w * 64 + n * 16 + l15;
                bfr[n] = *(const bf16x8*)(const void*)&B_lds[cn * 64 + (ke ^ ((cn & 7) << 3))];
            }
            #pragma unroll
            for (int m = 0; m < 4; ++m)
                #pragma unroll
                for (int n = 0; n < 4; ++n)
                    acc[m][n] = __builtin_amdgcn_mfma_f32_16x16x32_bf16(af[m], bfr[n], acc[m][n], 0, 0, 0);
        }
        __syncthreads();
    }

    float psum[4][4], psq[4][4];
    #pragma unroll
    for (int m = 0; m < 4; ++m)
        #pragma unroll
        for (int rr = 0; rr < 4; ++rr) { psum[m][rr] = 0.f; psq[m][rr] = 0.f; }
    #pragma unroll
    for (int m = 0; m < 4; ++m)
        #pragma unroll
        for (int n = 0; n < 4; ++n) {
            int col = w * 64 + n * 16 + l15;
            float bb = s_b3[col];
            #pragma unroll
            for (int rr = 0; rr < 4; ++rr) {
                float x = acc[m][n][rr] + bb;
                acc[m][n][rr] = x;
                psum[m][rr] += x;
                psq[m][rr] += x * x;
            }
        }
    #pragma unroll
    for (int m = 0; m < 4; ++m)
        #pragma unroll
        for (int rr = 0; rr < 4; ++rr) {
            float s = psum[m][rr], q = psq[m][rr];
            s += __shfl_xor(s, 1); s += __shfl_xor(s, 2); s += __shfl_xor(s, 4); s += __shfl_xor(s, 8);
            q += __shfl_xor(q, 1); q += __shfl_xor(q, 2); q += __shfl_xor(q, 4); q += __shfl_xor(q, 8);
            psum[m][rr] = s; psq[m][rr] = q;
        }
    float vs = 0.f, vq = 0.f;
    #pragma unroll
    for (int m = 0; m < 4; ++m)
        #pragma unroll
        for (int rr = 0; rr < 4; ++rr) {
            bool sel = (l15 == m * 4 + rr);
            vs = sel ? psum[m][rr] : vs;
            vq = sel ? psq[m][rr] : vq;
        }
    float (*s_part)[64][2] = (float(*)[64][2])(void*)M_lds;
    {
        int row = (l15 >> 2) * 16 + 4 * g + (l15 & 3);
        s_part[w][row][0] = vs;
        s_part[w][row][1] = vq;
    }
    __syncthreads();
    if (tid < 64) {
        float s = s_part[0][tid][0] + s_part[1][tid][0] + s_part[2][tid][0] + s_part[3][tid][0];
        float q = s_part[0][tid][1] + s_part[1][tid][1] + s_part[2][tid][1] + s_part[3][tid][1];
        float mean = s * (1.f / 256.f);
        float var = q * (1.f / 256.f) - mean * mean;
        s_mr[tid][0] = mean;
        s_mr[tid][1] = rsqrtf(var + 1e-5f);
    }
    __syncthreads();

    #pragma unroll
    for (int m = 0; m < 4; ++m)
        #pragma unroll
        for (int rr = 0; rr < 4; ++rr) {
            int row = m * 16 + 4 * g + rr;
            float mean = s_mr[row][0], rstd = s_mr[row][1];
            #pragma unroll
            for (int n = 0; n < 4; ++n) {
                int col = w * 64 + n * 16 + l15;
                float y = (acc[m][n][rr] - mean) * rstd * s_g2[col] + s_be2[col];
                float sy = y * (1.f / (1.f + __expf(-y)));
                M_lds[row * 256 + (col ^ ((row & 7) << 3))] = f2bf(sy);
            }
        }
    __syncthreads();

    f32x4 acc4[4][2] = {};
    for (int kt = 0; kt < 4; ++kt) {
        #pragma unroll
        for (int i = 0; i < 4; ++i) {
            int c = i * 256 + w * 64 + lane;
            int n = c >> 3, kbl = c & 7;
            int kb = kbl ^ (n & 7);
            const unsigned short* src = Wt4 + n * 256 + kt * 64 + kb * 8;
            gload16(src, &B_lds[(i * 256 + w * 64) * 8]);
        }
        __syncthreads();
        #pragma unroll
        for (int kk = 0; kk < 2; ++kk) {
            int keB = kk * 32 + 8 * g;
            int keA = kt * 64 + keB;
            bf16x8 af[4], bfr[2];
            #pragma unroll
            for (int m = 0; m < 4; ++m) {
                int r = m * 16 + l15;
                af[m] = *(const bf16x8*)(const void*)&M_lds[r * 256 + (keA ^ ((r & 7) << 3))];
            }
            #pragma unroll
            for (int n2 = 0; n2 < 2; ++n2) {
                int cn = w * 32 + n2 * 16 + l15;
                bfr[n2] = *(const bf16x8*)(const void*)&B_lds[cn * 64 + (keB ^ ((cn & 7) << 3))];
            }
            #pragma unroll
            for (int m = 0; m < 4; ++m)
                #pragma unroll
                for (int n2 = 0; n2 < 2; ++n2)
                    acc4[m][n2] = __builtin_amdgcn_mfma_f32_16x16x32_bf16(af[m], bfr[n2], acc4[m][n2], 0, 0, 0);
        }
        __syncthreads();
    }

    #pragma unroll
    for (int m = 0; m < 4; ++m)
        #pragma unroll
        for (int rr = 0; rr < 4; ++rr) {
            int row = m * 16 + 4 * g + rr;
            int nd = r0 + row;
            if (nd < NNODES) {
                #pragma unroll
                for (int n2 = 0; n2 < 2; ++n2) {
                    int col = w * 32 + n2 * 16 + l15;
                    out[(size_t)nd * NF + col] = h[(size_t)nd * NF + col] + acc4[m][n2][rr] + s_b4[col];
                }
            }
        }
}

extern "C" void kernel_launch(void* const* d_in, const int* in_sizes, int n_in,
                              void* d_out, int out_size, void* d_ws, size_t ws_size,
                              hipStream_t stream) {
    const float* h   = (const float*)d_in[0];
    const int* ei    = (const int*)d_in[1];
    const float* W1  = (const float*)d_in[2];
    const float* b1  = (const float*)d_in[3];
    const float* g1  = (const float*)d_in[4];
    const float* be1 = (const float*)d_in[5];
    const float* W2  = (const float*)d_in[6];
    const float* b2  = (const float*)d_in[7];
    const float* W3  = (const float*)d_in[8];
    const float* b3  = (const float*)d_in[9];
    const float* g2  = (const float*)d_in[10];
    const float* be2 = (const float*)d_in[11];
    const float* W4  = (const float*)d_in[12];
    const float* b4  = (const float*)d_in[13];
    float* out = (float*)d_out;

    char* ws = (char*)d_ws;
    float* agg            = (float*)(ws);                      // 51,200,000 B
    unsigned short* hbf   = (unsigned short*)(ws + 51200000);  // 12,800,000 B
    unsigned short* aggbf = (unsigned short*)(ws + 64000000);  // 25,600,000 B
    // ssrc/sdst overlay aggbf: live only [scatter, edge_kernel]; aggbf live [cvt2, node_kernel]
    int* ssrc             = (int*)(ws + 64000000);             // 3,200,000 B
    int* sdst             = (int*)(ws + 67200000);             // 3,200,000 B
    unsigned short* Wt1   = (unsigned short*)(ws + 89600000);  // 131,072 B
    unsigned short* Wt2   = (unsigned short*)(ws + 89731072);  // 131,072 B
    unsigned short* Wt3   = (unsigned short*)(ws + 89862144);  // 196,608 B
    unsigned short* Wt4   = (unsigned short*)(ws + 90058752);  // 65,536 B
    int* cnt              = (int*)(ws + 90124288);             // 200,000 B
    int* basep            = (int*)(ws + 90324288);             // 200,000 B
    int* cursor           = (int*)(ws + 90524288);             // 200,000 B

    hipMemsetAsync(agg, 0, (size_t)NNODES * NH * sizeof(float), stream);
    hipMemsetAsync(cnt, 0, NNODES * sizeof(int), stream);
    hipMemsetAsync(cursor, 0, NNODES * sizeof(int), stream);

    cvt_kernel<<<(NNODES * NF / 4 + 255) / 256, 256, 0, stream>>>(h, hbf, NNODES * NF / 4);
    tcvt_kernel<<<(256 * 256 + 255) / 256, 256, 0, stream>>>(W1, Wt1, 256, 256);
    tcvt_kernel<<<(256 * 256 + 255) / 256, 256, 0, stream>>>(W2, Wt2, 256, 256);
    tcvt_kernel<<<(384 * 256 + 255) / 256, 256, 0, stream>>>(W3, Wt3, 384, 256);
    tcvt_kernel<<<(256 * 128 + 255) / 256, 256, 0, stream>>>(W4, Wt4, 256, 128);

    hist_kernel<<<(NEDGES + 255) / 256, 256, 0, stream>>>(ei, cnt);
    scan_kernel<<<1, 1024, 0, stream>>>(cnt, basep, NNODES);
    scatter_kernel<<<(NEDGES + 255) / 256, 256, 0, stream>>>(ei, basep, cursor, ssrc, sdst);

    edge_kernel<<<NEDGES / 64, 256, 0, stream>>>(hbf, ssrc, sdst, Wt1, Wt2, b1, g1, be1, b2, agg);
    cvt_kernel<<<(NNODES * NH / 4 + 255) / 256, 256, 0, stream>>>(agg, aggbf, NNODES * NH / 4);
    node_kernel<<<(NNODES + 63) / 64, 256, 0, stream>>>(h, hbf, aggbf, Wt3, Wt4, b3, g2, be2, b4, out);
}

// Round 6
// 650.519 us; speedup vs baseline: 1.8638x; 1.2049x over previous
//
#include <hip/hip_runtime.h>
#include <hip/hip_bf16.h>
#include <stdint.h>

#define NNODES 50000
#define NEDGES 800000
#define NF 128
#define NH 256

typedef __attribute__((ext_vector_type(8))) __bf16 bf16x8;
typedef __attribute__((ext_vector_type(8))) unsigned short u16x8;
typedef __attribute__((ext_vector_type(4))) float f32x4;

__device__ __forceinline__ unsigned short f2bf(float f) {
    union { float f; unsigned int u; } v; v.f = f;
    unsigned int r = v.u + 0x7fffu + ((v.u >> 16) & 1u);
    return (unsigned short)(r >> 16);
}

__device__ __forceinline__ void gload16(const void* g, void* l) {
    __builtin_amdgcn_global_load_lds(
        (const __attribute__((address_space(1))) void*)g,
        (__attribute__((address_space(3))) void*)l,
        16, 0, 0);
}

// W [K][Nn] f32 row-major -> Wt [Nn][K] bf16
__global__ __launch_bounds__(256) void tcvt_kernel(const float* __restrict__ W,
                                                   unsigned short* __restrict__ Wt, int K, int Nn) {
    int i = blockIdx.x * 256 + threadIdx.x;
    if (i < K * Nn) {
        int k = i / Nn, n = i - k * Nn;
        Wt[n * K + k] = f2bf(W[i]);
    }
}

// W1 [256][256] f32 -> Wtpq [512][128] bf16 : n<256 -> W1a col n; n>=256 -> W1b col n-256
__global__ __launch_bounds__(256) void wpq_kernel(const float* __restrict__ W1,
                                                  unsigned short* __restrict__ Wtpq) {
    int i = blockIdx.x * 256 + threadIdx.x;
    if (i < 512 * 128) {
        int n = i >> 7, k = i & 127;
        float v = (n < 256) ? W1[k * 256 + n] : W1[(128 + k) * 256 + (n - 256)];
        Wtpq[i] = f2bf(v);
    }
}

// ---------------- sort-by-row kernels ----------------
__global__ __launch_bounds__(256) void hist_kernel(const int* __restrict__ row, int* __restrict__ cnt) {
    int e = blockIdx.x * 256 + threadIdx.x;
    if (e < NEDGES) atomicAdd(&cnt[row[e]], 1);
}

__global__ __launch_bounds__(1024) void scan_kernel(const int* __restrict__ cnt, int* __restrict__ base, int n) {
    __shared__ int wsum[16];
    __shared__ int s_carry;
    const int tid = threadIdx.x;
    const int lane = tid & 63;
    const int wv = tid >> 6;
    if (tid == 0) s_carry = 0;
    __syncthreads();
    for (int off = 0; off < n; off += 1024) {
        int v = (off + tid < n) ? cnt[off + tid] : 0;
        int acc = v;
        #pragma unroll
        for (int s = 1; s < 64; s <<= 1) {
            int t = __shfl_up(acc, s);
            if (lane >= s) acc += t;
        }
        if (lane == 63) wsum[wv] = acc;
        __syncthreads();
        if (wv == 0) {
            int x = (lane < 16) ? wsum[lane] : 0;
            #pragma unroll
            for (int s = 1; s < 16; s <<= 1) {
                int t = __shfl_up(x, s);
                if (lane >= s) x += t;
            }
            if (lane < 16) wsum[lane] = x;
        }
        __syncthreads();
        int c = s_carry;
        int wtot = __shfl(acc, 63);
        int woff = wsum[wv] - wtot;
        if (off + tid < n) base[off + tid] = c + woff + acc - v;
        __syncthreads();
        if (tid == 0) s_carry = c + wsum[15];
        __syncthreads();
    }
}

__global__ __launch_bounds__(256) void scatter_kernel(const int* __restrict__ ei,
                                                      const int* __restrict__ base,
                                                      int* __restrict__ cursor,
                                                      unsigned short* __restrict__ ssrc,
                                                      unsigned short* __restrict__ sdst) {
    int e = blockIdx.x * 256 + threadIdx.x;
    if (e < NEDGES) {
        int r = ei[e];
        int c = ei[NEDGES + e];
        int pos = base[r] + atomicAdd(&cursor[r], 1);
        ssrc[pos] = (unsigned short)r;
        sdst[pos] = (unsigned short)c;
    }
}

// ---------------- P/Q precompute ----------------
// P = h@W1a + b1, Q = h@W1b  (both [NNODES][256] bf16). BM=64, K=128, 4 waves.
__global__ __launch_bounds__(256, 2)
void pq_kernel(const float* __restrict__ h,
               const unsigned short* __restrict__ Wtpq,
               const float* __restrict__ b1,
               unsigned short* __restrict__ P,
               unsigned short* __restrict__ Q)
{
    __shared__ __align__(16) unsigned short A_lds[64 * 128];
    const int tid = threadIdx.x;
    const int lane = tid & 63;
    const int w = tid >> 6;
    const int l15 = lane & 15;
    const int g = lane >> 4;
    const int r0 = blockIdx.x * 64;

    float b1r[4];
    #pragma unroll
    for (int n = 0; n < 4; ++n) b1r[n] = b1[w * 64 + n * 16 + l15];

    // reg-stage A (h f32 -> bf16, swizzled chunks)
    #pragma unroll
    for (int i = 0; i < 4; ++i) {
        int idx = i * 256 + tid;
        int row = idx >> 4, cl = idx & 15;
        int nd = r0 + row; if (nd >= NNODES) nd = NNODES - 1;
        const float* sp = h + (size_t)nd * NF + ((cl ^ (row & 7)) * 8);
        float4 va = *(const float4*)sp;
        float4 vb = *(const float4*)(sp + 4);
        u16x8 mv;
        mv[0] = f2bf(va.x); mv[1] = f2bf(va.y); mv[2] = f2bf(va.z); mv[3] = f2bf(va.w);
        mv[4] = f2bf(vb.x); mv[5] = f2bf(vb.y); mv[6] = f2bf(vb.z); mv[7] = f2bf(vb.w);
        *(u16x8*)(void*)&A_lds[row * 128 + cl * 8] = mv;
    }
    __syncthreads();

    #pragma unroll
    for (int p = 0; p < 2; ++p) {
        bf16x8 Bf[4][4];
        #pragma unroll
        for (int n = 0; n < 4; ++n) {
            int cn = w * 64 + n * 16 + l15;
            #pragma unroll
            for (int ks = 0; ks < 4; ++ks)
                Bf[n][ks] = *(const bf16x8*)(const void*)&Wtpq[(size_t)(p * 256 + cn) * 128 + ks * 32 + 8 * g];
        }
        f32x4 acc[4][4] = {};
        #pragma unroll
        for (int ks = 0; ks < 4; ++ks) {
            bf16x8 af[4];
            #pragma unroll
            for (int m = 0; m < 4; ++m) {
                int r = m * 16 + l15;
                af[m] = *(const bf16x8*)(const void*)&A_lds[r * 128 + ((ks * 32 + 8 * g) ^ ((r & 7) << 3))];
            }
            #pragma unroll
            for (int m = 0; m < 4; ++m)
                #pragma unroll
                for (int n = 0; n < 4; ++n)
                    acc[m][n] = __builtin_amdgcn_mfma_f32_16x16x32_bf16(af[m], Bf[n][ks], acc[m][n], 0, 0, 0);
        }
        unsigned short* dst = p ? Q : P;
        #pragma unroll
        for (int m = 0; m < 4; ++m)
            #pragma unroll
            for (int rr = 0; rr < 4; ++rr) {
                int row = m * 16 + 4 * g + rr;
                int nd = r0 + row;
                if (nd < NNODES) {
                    #pragma unroll
                    for (int n = 0; n < 4; ++n) {
                        int col = w * 64 + n * 16 + l15;
                        float v = acc[m][n][rr] + (p ? 0.f : b1r[n]);
                        dst[(size_t)nd * NH + col] = f2bf(v);
                    }
                }
            }
    }
}

// ---------------- edge kernel ----------------
// 64 sorted edges/block, 4 waves. Per edge: x = P[src]+Q[tgt] (gather, no GEMM1),
// LN+SiLU -> M tile, GEMM2 (W2 frags in regs), S-tile run-reduce epilogue.
__global__ __launch_bounds__(256, 2)
void edge_kernel(const unsigned short* __restrict__ P,
                 const unsigned short* __restrict__ Q,
                 const unsigned short* __restrict__ ssrc,
                 const unsigned short* __restrict__ sdst,
                 const unsigned short* __restrict__ Wt2,
                 const float* __restrict__ g1, const float* __restrict__ be1,
                 const float* __restrict__ b2,
                 float* __restrict__ agg)
{
    // M (32768 B) ; S f32 64x260 (66560 B) overlays after GEMM2
    __shared__ __align__(16) char smem[66560];
    unsigned short* M_lds = (unsigned short*)smem;
    float* S = (float*)smem;
    __shared__ unsigned short s_src[64];
    __shared__ float s_mr[64][2];
    __shared__ float s_part[4][64][2];
    __shared__ float s_g1[256], s_be1[256];

    const int tid = threadIdx.x;
    const int lane = tid & 63;
    const int w = tid >> 6;
    const int l15 = lane & 15;
    const int g = lane >> 4;
    const int e0 = blockIdx.x * 64;
    const int r = lane;  // thread's row (edge slot); wave w owns cols [w*64, w*64+64)

    s_g1[tid] = g1[tid]; s_be1[tid] = be1[tid];
    if (tid < 64) s_src[tid] = ssrc[e0 + tid];

    float b2r[4];
    #pragma unroll
    for (int n = 0; n < 4; ++n) b2r[n] = b2[w * 64 + n * 16 + l15];

    // ---- gather x = P[src] + Q[tgt] for this thread's 64 cols; stats on the fly ----
    int nds = ssrc[e0 + r];
    int ndt = sdst[e0 + r];
    const bf16x8* Pp = (const bf16x8*)(const void*)(P + (size_t)nds * NH + w * 64);
    const bf16x8* Qp = (const bf16x8*)(const void*)(Q + (size_t)ndt * NH + w * 64);

    float x[8][8];
    float sum = 0.f, sq = 0.f;
    #pragma unroll
    for (int j = 0; j < 8; ++j) {
        bf16x8 pv = Pp[j];
        bf16x8 qv = Qp[j];
        #pragma unroll
        for (int k = 0; k < 8; ++k) {
            float xx = (float)pv[k] + (float)qv[k];
            x[j][k] = xx;
            sum += xx;
            sq += xx * xx;
        }
    }
    s_part[w][r][0] = sum;
    s_part[w][r][1] = sq;
    __syncthreads();                                   // B1
    if (tid < 64) {
        float s = s_part[0][tid][0] + s_part[1][tid][0] + s_part[2][tid][0] + s_part[3][tid][0];
        float q = s_part[0][tid][1] + s_part[1][tid][1] + s_part[2][tid][1] + s_part[3][tid][1];
        float mean = s * (1.f / 256.f);
        float var = q * (1.f / 256.f) - mean * mean;
        s_mr[tid][0] = mean;
        s_mr[tid][1] = rsqrtf(var + 1e-5f);
    }
    __syncthreads();                                   // B2

    // ---- W2 fragments -> regs (latency hides under LN apply) ----
    bf16x8 Bf[4][8];
    #pragma unroll
    for (int n = 0; n < 4; ++n) {
        int cn = w * 64 + n * 16 + l15;
        #pragma unroll
        for (int ks = 0; ks < 8; ++ks)
            Bf[n][ks] = *(const bf16x8*)(const void*)&Wt2[cn * 256 + ks * 32 + 8 * g];
    }

    // ---- LN apply + SiLU -> M tile (bf16, swizzled b128 chunk writes) ----
    {
        float mean = s_mr[r][0], rstd = s_mr[r][1];
        #pragma unroll
        for (int j = 0; j < 8; ++j) {
            u16x8 mv;
            #pragma unroll
            for (int k = 0; k < 8; ++k) {
                int col = w * 64 + j * 8 + k;
                float y = (x[j][k] - mean) * rstd * s_g1[col] + s_be1[col];
                float sy = y * (1.f / (1.f + __expf(-y)));
                mv[k] = f2bf(sy);
            }
            *(u16x8*)(void*)&M_lds[r * 256 + w * 64 + ((j ^ (r & 7)) * 8)] = mv;
        }
    }
    __syncthreads();                                   // B3: M ready

    // ---- GEMM2: m[64x256] @ W2 ----
    f32x4 acc2[4][4] = {};
    #pragma unroll
    for (int ks = 0; ks < 8; ++ks) {
        bf16x8 af[4];
        #pragma unroll
        for (int m = 0; m < 4; ++m) {
            int rr_ = m * 16 + l15;
            af[m] = *(const bf16x8*)(const void*)&M_lds[rr_ * 256 + ((ks * 32 + 8 * g) ^ ((rr_ & 7) << 3))];
        }
        #pragma unroll
        for (int m = 0; m < 4; ++m)
            #pragma unroll
            for (int n = 0; n < 4; ++n)
                acc2[m][n] = __builtin_amdgcn_mfma_f32_16x16x32_bf16(af[m], Bf[n][ks], acc2[m][n], 0, 0, 0);
    }
    __syncthreads();                                   // B4: M reads done, S may overlay

    // ---- S tile (f32, stride 260) ----
    #pragma unroll
    for (int m = 0; m < 4; ++m)
        #pragma unroll
        for (int rr = 0; rr < 4; ++rr) {
            int row = m * 16 + 4 * g + rr;
            #pragma unroll
            for (int n = 0; n < 4; ++n) {
                int col = w * 64 + n * 16 + l15;
                S[row * 260 + col] = acc2[m][n][rr] + b2r[n];
            }
        }
    __syncthreads();                                   // B5: S ready

    // ---- per-column run-reduce over sorted rows, one atomic per run ----
    {
        int col = tid;
        float run = 0.f;
        int prev = s_src[0];
        #pragma unroll 1
        for (int rr = 0; rr < 64; ++rr) {
            int nd = s_src[rr];
            if (nd != prev) {
                atomicAdd(&agg[(size_t)prev * NH + col], run);
                run = 0.f;
                prev = nd;
            }
            run += S[rr * 260 + col];
        }
        atomicAdd(&agg[(size_t)prev * NH + col], run);
    }
}

// ---------------- node kernel ----------------
__global__ __launch_bounds__(256, 2)
void node_kernel(const float* __restrict__ h,
                 const float* __restrict__ agg,
                 const unsigned short* __restrict__ Wt3,
                 const unsigned short* __restrict__ Wt4,
                 const float* __restrict__ b3, const float* __restrict__ g2,
                 const float* __restrict__ be2, const float* __restrict__ b4,
                 float* __restrict__ out)
{
    __shared__ __align__(16) unsigned short A_lds[64 * 64];
    __shared__ __align__(16) unsigned short B_lds[256 * 64];
    __shared__ __align__(16) unsigned short M_lds[64 * 256];
    __shared__ float s_mr[64][2];
    __shared__ float s_b3[256], s_g2[256], s_be2[256], s_b4[128];

    const int tid = threadIdx.x;
    const int lane = tid & 63;
    const int w = tid >> 6;
    const int l15 = lane & 15;
    const int g = lane >> 4;
    const int r0 = blockIdx.x * 64;

    s_b3[tid] = b3[tid]; s_g2[tid] = g2[tid]; s_be2[tid] = be2[tid];
    if (tid < 128) s_b4[tid] = b4[tid];
    __syncthreads();

    f32x4 acc[4][4] = {};

    for (int kt = 0; kt < 6; ++kt) {
        // B stage (gload16)
        #pragma unroll
        for (int i = 0; i < 8; ++i) {
            int c = i * 256 + w * 64 + lane;
            int n = c >> 3, kbl = c & 7;
            int kb = kbl ^ (n & 7);
            const unsigned short* src = Wt3 + n * 384 + kt * 64 + kb * 8;
            gload16(src, &B_lds[(i * 256 + w * 64) * 8]);
        }
        // A reg-stage (f32 -> bf16, swizzled chunks)
        #pragma unroll
        for (int i = 0; i < 2; ++i) {
            int idx = i * 256 + tid;
            int row = idx >> 3, cl = idx & 7;
            int nd = r0 + row; if (nd >= NNODES) nd = NNODES - 1;
            int scol = (cl ^ (row & 7)) * 8;
            const float* sp = (kt < 2) ? (h + (size_t)nd * NF + kt * 64 + scol)
                                       : (agg + (size_t)nd * NH + (kt - 2) * 64 + scol);
            float4 va = *(const float4*)sp;
            float4 vb = *(const float4*)(sp + 4);
            u16x8 mv;
            mv[0] = f2bf(va.x); mv[1] = f2bf(va.y); mv[2] = f2bf(va.z); mv[3] = f2bf(va.w);
            mv[4] = f2bf(vb.x); mv[5] = f2bf(vb.y); mv[6] = f2bf(vb.z); mv[7] = f2bf(vb.w);
            *(u16x8*)(void*)&A_lds[row * 64 + cl * 8] = mv;
        }
        __syncthreads();
        #pragma unroll
        for (int kk = 0; kk < 2; ++kk) {
            int ke = kk * 32 + 8 * g;
            bf16x8 af[4], bfr[4];
            #pragma unroll
            for (int m = 0; m < 4; ++m) {
                int rr_ = m * 16 + l15;
                af[m] = *(const bf16x8*)(const void*)&A_lds[rr_ * 64 + (ke ^ ((rr_ & 7) << 3))];
            }
            #pragma unroll
            for (int n = 0; n < 4; ++n) {
                int cn = w * 64 + n * 16 + l15;
                bfr[n] = *(const bf16x8*)(const void*)&B_lds[cn * 64 + (ke ^ ((cn & 7) << 3))];
            }
            #pragma unroll
            for (int m = 0; m < 4; ++m)
                #pragma unroll
                for (int n = 0; n < 4; ++n)
                    acc[m][n] = __builtin_amdgcn_mfma_f32_16x16x32_bf16(af[m], bfr[n], acc[m][n], 0, 0, 0);
        }
        __syncthreads();
    }

    float psum[4][4], psq[4][4];
    #pragma unroll
    for (int m = 0; m < 4; ++m)
        #pragma unroll
        for (int rr = 0; rr < 4; ++rr) { psum[m][rr] = 0.f; psq[m][rr] = 0.f; }
    #pragma unroll
    for (int m = 0; m < 4; ++m)
        #pragma unroll
        for (int n = 0; n < 4; ++n) {
            int col = w * 64 + n * 16 + l15;
            float bb = s_b3[col];
            #pragma unroll
            for (int rr = 0; rr < 4; ++rr) {
                float xv = acc[m][n][rr] + bb;
                acc[m][n][rr] = xv;
                psum[m][rr] += xv;
                psq[m][rr] += xv * xv;
            }
        }
    #pragma unroll
    for (int m = 0; m < 4; ++m)
        #pragma unroll
        for (int rr = 0; rr < 4; ++rr) {
            float s = psum[m][rr], q = psq[m][rr];
            s += __shfl_xor(s, 1); s += __shfl_xor(s, 2); s += __shfl_xor(s, 4); s += __shfl_xor(s, 8);
            q += __shfl_xor(q, 1); q += __shfl_xor(q, 2); q += __shfl_xor(q, 4); q += __shfl_xor(q, 8);
            psum[m][rr] = s; psq[m][rr] = q;
        }
    float vs = 0.f, vq = 0.f;
    #pragma unroll
    for (int m = 0; m < 4; ++m)
        #pragma unroll
        for (int rr = 0; rr < 4; ++rr) {
            bool sel = (l15 == m * 4 + rr);
            vs = sel ? psum[m][rr] : vs;
            vq = sel ? psq[m][rr] : vq;
        }
    float (*s_part)[64][2] = (float(*)[64][2])(void*)M_lds;
    {
        int row = (l15 >> 2) * 16 + 4 * g + (l15 & 3);
        s_part[w][row][0] = vs;
        s_part[w][row][1] = vq;
    }
    __syncthreads();
    if (tid < 64) {
        float s = s_part[0][tid][0] + s_part[1][tid][0] + s_part[2][tid][0] + s_part[3][tid][0];
        float q = s_part[0][tid][1] + s_part[1][tid][1] + s_part[2][tid][1] + s_part[3][tid][1];
        float mean = s * (1.f / 256.f);
        float var = q * (1.f / 256.f) - mean * mean;
        s_mr[tid][0] = mean;
        s_mr[tid][1] = rsqrtf(var + 1e-5f);
    }
    __syncthreads();

    #pragma unroll
    for (int m = 0; m < 4; ++m)
        #pragma unroll
        for (int rr = 0; rr < 4; ++rr) {
            int row = m * 16 + 4 * g + rr;
            float mean = s_mr[row][0], rstd = s_mr[row][1];
            #pragma unroll
            for (int n = 0; n < 4; ++n) {
                int col = w * 64 + n * 16 + l15;
                float y = (acc[m][n][rr] - mean) * rstd * s_g2[col] + s_be2[col];
                float sy = y * (1.f / (1.f + __expf(-y)));
                M_lds[row * 256 + (col ^ ((row & 7) << 3))] = f2bf(sy);
            }
        }
    __syncthreads();

    f32x4 acc4[4][2] = {};
    for (int kt = 0; kt < 4; ++kt) {
        #pragma unroll
        for (int i = 0; i < 4; ++i) {
            int c = i * 256 + w * 64 + lane;
            int n = c >> 3, kbl = c & 7;
            int kb = kbl ^ (n & 7);
            const unsigned short* src = Wt4 + n * 256 + kt * 64 + kb * 8;
            gload16(src, &B_lds[(i * 256 + w * 64) * 8]);
        }
        __syncthreads();
        #pragma unroll
        for (int kk = 0; kk < 2; ++kk) {
            int keB = kk * 32 + 8 * g;
            int keA = kt * 64 + keB;
            bf16x8 af[4], bfr[2];
            #pragma unroll
            for (int m = 0; m < 4; ++m) {
                int rr_ = m * 16 + l15;
                af[m] = *(const bf16x8*)(const void*)&M_lds[rr_ * 256 + (keA ^ ((rr_ & 7) << 3))];
            }
            #pragma unroll
            for (int n2 = 0; n2 < 2; ++n2) {
                int cn = w * 32 + n2 * 16 + l15;
                bfr[n2] = *(const bf16x8*)(const void*)&B_lds[cn * 64 + (keB ^ ((cn & 7) << 3))];
            }
            #pragma unroll
            for (int m = 0; m < 4; ++m)
                #pragma unroll
                for (int n2 = 0; n2 < 2; ++n2)
                    acc4[m][n2] = __builtin_amdgcn_mfma_f32_16x16x32_bf16(af[m], bfr[n2], acc4[m][n2], 0, 0, 0);
        }
        __syncthreads();
    }

    #pragma unroll
    for (int m = 0; m < 4; ++m)
        #pragma unroll
        for (int rr = 0; rr < 4; ++rr) {
            int row = m * 16 + 4 * g + rr;
            int nd = r0 + row;
            if (nd < NNODES) {
                #pragma unroll
                for (int n2 = 0; n2 < 2; ++n2) {
                    int col = w * 32 + n2 * 16 + l15;
                    out[(size_t)nd * NF + col] = h[(size_t)nd * NF + col] + acc4[m][n2][rr] + s_b4[col];
                }
            }
        }
}

extern "C" void kernel_launch(void* const* d_in, const int* in_sizes, int n_in,
                              void* d_out, int out_size, void* d_ws, size_t ws_size,
                              hipStream_t stream) {
    const float* h   = (const float*)d_in[0];
    const int* ei    = (const int*)d_in[1];
    const float* W1  = (const float*)d_in[2];
    const float* b1  = (const float*)d_in[3];
    const float* g1  = (const float*)d_in[4];
    const float* be1 = (const float*)d_in[5];
    const float* W2  = (const float*)d_in[6];
    const float* b2  = (const float*)d_in[7];
    const float* W3  = (const float*)d_in[8];
    const float* b3  = (const float*)d_in[9];
    const float* g2  = (const float*)d_in[10];
    const float* be2 = (const float*)d_in[11];
    const float* W4  = (const float*)d_in[12];
    const float* b4  = (const float*)d_in[13];
    float* out = (float*)d_out;

    char* ws = (char*)d_ws;
    float* agg            = (float*)(ws);                      // 51,200,000 B [edge->node]
    // cnt/basep/cursor overlay agg: live only [hist -> scatter], agg memset after
    int* cnt              = (int*)(ws);                        // 200,000 B
    int* basep            = (int*)(ws + 200000);               // 200,000 B
    int* cursor           = (int*)(ws + 400000);               // 200,000 B
    unsigned short* P     = (unsigned short*)(ws + 51200000);  // 25,600,000 B [pq->edge]
    unsigned short* Q     = (unsigned short*)d_out;            // 25,600,000 B [pq->edge], dead before node writes out
    unsigned short* ssrc  = (unsigned short*)(ws + 76800000);  // 1,600,000 B
    unsigned short* sdst  = (unsigned short*)(ws + 78400000);  // 1,600,000 B
    unsigned short* Wtpq  = (unsigned short*)(ws + 80000000);  // 131,072 B
    unsigned short* Wt2   = (unsigned short*)(ws + 80131072);  // 131,072 B
    unsigned short* Wt3   = (unsigned short*)(ws + 80262144);  // 196,608 B
    unsigned short* Wt4   = (unsigned short*)(ws + 80458752);  // 65,536 B  (end ~80.5 MB)

    hipMemsetAsync(ws, 0, 600000, stream);  // zero cnt/basep/cursor

    wpq_kernel<<<(512 * 128 + 255) / 256, 256, 0, stream>>>(W1, Wtpq);
    tcvt_kernel<<<(256 * 256 + 255) / 256, 256, 0, stream>>>(W2, Wt2, 256, 256);
    tcvt_kernel<<<(384 * 256 + 255) / 256, 256, 0, stream>>>(W3, Wt3, 384, 256);
    tcvt_kernel<<<(256 * 128 + 255) / 256, 256, 0, stream>>>(W4, Wt4, 256, 128);

    hist_kernel<<<(NEDGES + 255) / 256, 256, 0, stream>>>(ei, cnt);
    scan_kernel<<<1, 1024, 0, stream>>>(cnt, basep, NNODES);
    scatter_kernel<<<(NEDGES + 255) / 256, 256, 0, stream>>>(ei, basep, cursor, ssrc, sdst);

    pq_kernel<<<(NNODES + 63) / 64, 256, 0, stream>>>(h, Wtpq, b1, P, Q);

    hipMemsetAsync(agg, 0, (size_t)NNODES * NH * sizeof(float), stream);  // cnt region dead now

    edge_kernel<<<NEDGES / 64, 256, 0, stream>>>(P, Q, ssrc, sdst, Wt2, g1, be1, b2, agg);
    node_kernel<<<(NNODES + 63) / 64, 256, 0, stream>>>(h, agg, Wt3, Wt4, b3, g2, be2, b4, out);
}